// Round 7
// baseline (174.748 us; speedup 1.0000x reference)
//
#include <hip/hip_runtime.h>

#define NBLK 1024         // partition blocks
#define PTH  512          // pcount/pfill threads
#define SH   9
#define BUCK 512          // nodes per bucket = 1<<SH
#define NBUK_MAX 512
#define SCB  512          // scanA block width
#define PREP_CAP 10240    // max staged edges per bucket in k_prep (40KB LDS)

// ============ PATH A: bucket sort -> exact CSR -> multi-lane register gathers ============

// Pass A: per-block LDS histogram of dst buckets -> hist2d[bucket*NBLK + block]
__global__ void __launch_bounds__(PTH) k_pcount(const int* __restrict__ dst,
                                                int* __restrict__ hist2d,
                                                int E, int nbuk, int chunk) {
    __shared__ int h[NBUK_MAX];
    for (int t = threadIdx.x; t < nbuk; t += PTH) h[t] = 0;
    __syncthreads();
    int beg = blockIdx.x * chunk, end = min(beg + chunk, E);
    for (int i = beg + threadIdx.x; i < end; i += PTH)
        atomicAdd(&h[dst[i] >> SH], 1);
    __syncthreads();
    for (int t = threadIdx.x; t < nbuk; t += PTH)
        hist2d[t * NBLK + blockIdx.x] = h[t];
}

// 512-wide block exclusive scan -> partials + block sums
__global__ void __launch_bounds__(SCB) k_scanA(const int* __restrict__ in,
                                               int* __restrict__ outp,
                                               int* __restrict__ bsum, int M) {
    __shared__ int s[SCB];
    int t = threadIdx.x, i = blockIdx.x * SCB + t;
    int h = (i < M) ? in[i] : 0;
    s[t] = h; __syncthreads();
    for (int off = 1; off < SCB; off <<= 1) {
        int v = (t >= off) ? s[t - off] : 0;
        __syncthreads();
        s[t] += v;
        __syncthreads();
    }
    if (i < M) outp[i] = s[t] - h;
    if (t == SCB - 1) bsum[blockIdx.x] = s[SCB - 1];
}

__global__ void k_scanB(const int* __restrict__ bsum, int* __restrict__ bsum_ex, int NB) {
    __shared__ int s[1024];
    int t = threadIdx.x;
    int v = (t < NB) ? bsum[t] : 0;
    s[t] = v; __syncthreads();
    for (int off = 1; off < 1024; off <<= 1) {
        int u = (t >= off) ? s[t - off] : 0;
        __syncthreads();
        s[t] += u;
        __syncthreads();
    }
    if (t < NB) bsum_ex[t] = s[t] - v;
}

__device__ __forceinline__ int scan_off(const int* rs2, const int* bse, int j) {
    return rs2[j] + bse[j >> 9];          // SCB=512
}

// Pass B: LDS cursors, write packed (src<<SH | dst_low) in bucket-partitioned order
__global__ void __launch_bounds__(PTH) k_pfill(const int* __restrict__ src,
                                               const int* __restrict__ dst,
                                               const int* __restrict__ rs2,
                                               const int* __restrict__ bse,
                                               int* __restrict__ part,
                                               int E, int nbuk, int chunk) {
    __shared__ int cur[NBUK_MAX];
    for (int t = threadIdx.x; t < nbuk; t += PTH)
        cur[t] = scan_off(rs2, bse, t * NBLK + blockIdx.x);
    __syncthreads();
    int beg = blockIdx.x * chunk, end = min(beg + chunk, E);
    for (int i = beg + threadIdx.x; i < end; i += PTH) {
        int d = dst[i];
        int pos = atomicAdd(&cur[d >> SH], 1);     // LDS atomic
        part[pos] = (src[i] << SH) | (d & (BUCK - 1));
    }
}

// per bucket: per-node hist -> scan -> scatter src into dst-sorted part2 (LDS-staged,
// coalesced global write); also rowstart (absolute), dinv, xw = dinv*x
__global__ void __launch_bounds__(512) k_prep(
        const int* __restrict__ part, const int* __restrict__ rs2,
        const int* __restrict__ bse, const float* __restrict__ x,
        int* __restrict__ part2, int* __restrict__ rowstart,
        float* __restrict__ dinv, float2* __restrict__ xw,
        int n, int nbuk, int E) {
    __shared__ int hist[BUCK];
    __shared__ int s[BUCK];
    __shared__ int cur[BUCK];
    __shared__ int outbuf[PREP_CAP];
    int t = threadIdx.x, b = blockIdx.x;
    hist[t] = 0;
    __syncthreads();
    int beg = scan_off(rs2, bse, b * NBLK);
    int end = (b + 1 < nbuk) ? scan_off(rs2, bse, (b + 1) * NBLK) : E;
    for (int i = beg + t; i < end; i += 512)
        atomicAdd(&hist[part[i] & (BUCK - 1)], 1);
    __syncthreads();
    s[t] = hist[t];
    __syncthreads();
    for (int d = 1; d < 512; d <<= 1) {
        int v = (t >= d) ? s[t - d] : 0;
        __syncthreads();
        s[t] += v;
        __syncthreads();
    }
    int excl = s[t] - hist[t];
    cur[t] = beg + excl;
    int node = (b << SH) + t;
    rowstart[node] = beg + excl;
    if (node < n) {
        float di = rsqrtf((float)hist[t] + 1.0f);
        dinv[node] = di;
        float2 xs = *reinterpret_cast<const float2*>(&x[2 * node]);
        xw[node] = make_float2(di * xs.x, di * xs.y);
    }
    __syncthreads();
    int cnt = end - beg;
    bool staged = (cnt <= PREP_CAP);
    if (staged) {
        for (int i = beg + t; i < end; i += 512) {
            int e = part[i];
            int p = atomicAdd(&cur[e & (BUCK - 1)], 1);
            outbuf[p - beg] = e >> SH;
        }
        __syncthreads();
        for (int i = t; i < cnt; i += 512)
            part2[beg + i] = outbuf[i];             // coalesced
    } else {
        for (int i = beg + t; i < end; i += 512) {
            int e = part[i];
            int p = atomicAdd(&cur[e & (BUCK - 1)], 1);
            part2[p] = e >> SH;
        }
    }
}

// layer-1: 4 lanes/node gather (prefetched) + butterfly, MLP split 16 hidden/lane
__global__ void __launch_bounds__(256) k_bz(
        const int* __restrict__ part2, const int* __restrict__ rowstart,
        const float* __restrict__ dinv, const float2* __restrict__ xw,
        const float* __restrict__ W1, const float* __restrict__ b1,
        const float* __restrict__ W2, float4* __restrict__ zw, int n) {
    __shared__ float sW1[128], sb1[64], sW2[192];
    for (int t = threadIdx.x; t < 128; t += 256) sW1[t] = W1[t];
    for (int t = threadIdx.x; t < 64;  t += 256) sb1[t] = b1[t];
    for (int t = threadIdx.x; t < 192; t += 256) sW2[t] = W2[t];
    __syncthreads();
    int tid = blockIdx.x * 256 + threadIdx.x;
    int i = tid >> 2, lane = tid & 3;
    if (i >= n) return;
    int beg = rowstart[i], end = rowstart[i + 1];
    float a0 = 0.f, a1 = 0.f;
    int e = beg + lane;
    int sn = (e < end) ? part2[e] : 0;
    while (e < end) {                              // prefetch next index
        int scur = sn, en = e + 4;
        sn = (en < end) ? part2[en] : 0;
        float2 v = xw[scur];
        a0 += v.x; a1 += v.y;
        e = en;
    }
    if (lane == 0) {                               // self-loop term once
        float2 self = xw[i];
        a0 += self.x; a1 += self.y;
    }
    a0 += __shfl_xor(a0, 1); a0 += __shfl_xor(a0, 2);
    a1 += __shfl_xor(a1, 1); a1 += __shfl_xor(a1, 2);
    float di = dinv[i];
    a0 *= di; a1 *= di;
    float z0 = 0.f, z1 = 0.f, z2 = 0.f;
    int j0 = lane << 4;
#pragma unroll
    for (int jj = 0; jj < 16; ++jj) {
        int j = j0 + jj;
        float h = fmaf(a0, sW1[j], fmaf(a1, sW1[64 + j], sb1[j]));
        h = fmaxf(h, 0.f);
        z0 = fmaf(h, sW2[3 * j],     z0);
        z1 = fmaf(h, sW2[3 * j + 1], z1);
        z2 = fmaf(h, sW2[3 * j + 2], z2);
    }
    z0 += __shfl_xor(z0, 1); z0 += __shfl_xor(z0, 2);
    z1 += __shfl_xor(z1, 1); z1 += __shfl_xor(z1, 2);
    z2 += __shfl_xor(z2, 1); z2 += __shfl_xor(z2, 2);
    if (lane == 0)
        zw[i] = make_float4(di * z0, di * z1, di * z2, 0.f);   // pre-scaled payload
}

// layer-2: 8 lanes/node gather (prefetched) + butterfly; epilogue + wave pooling
__global__ void __launch_bounds__(256) k_bout(
        const int* __restrict__ part2, const int* __restrict__ rowstart,
        const float* __restrict__ dinv, const float4* __restrict__ zw,
        const float* __restrict__ b2, const int* __restrict__ batch,
        float* __restrict__ pooled, float* __restrict__ cnt, int n) {
    int tid = blockIdx.x * 256 + threadIdx.x;
    int i = tid >> 3, lane = tid & 7;
    float o0 = 0.f, o1 = 0.f, o2 = 0.f, vc = 0.f;
    int g = -1;
    if (i < n) {
        int beg = rowstart[i], end = rowstart[i + 1];
        float a0 = 0.f, a1 = 0.f, a2 = 0.f;
        int e = beg + lane;
        int sn = (e < end) ? part2[e] : 0;
        while (e < end) {
            int scur = sn, en = e + 8;
            sn = (en < end) ? part2[en] : 0;
            float4 v = zw[scur];
            a0 += v.x; a1 += v.y; a2 += v.z;
            e = en;
        }
        if (lane == 0) {
            float4 self = zw[i];
            a0 += self.x; a1 += self.y; a2 += self.z;
        }
        a0 += __shfl_xor(a0, 1); a0 += __shfl_xor(a0, 2); a0 += __shfl_xor(a0, 4);
        a1 += __shfl_xor(a1, 1); a1 += __shfl_xor(a1, 2); a1 += __shfl_xor(a1, 4);
        a2 += __shfl_xor(a2, 1); a2 += __shfl_xor(a2, 2); a2 += __shfl_xor(a2, 4);
        if (lane == 0) {                            // one contribution per node
            float di = dinv[i];
            o0 = fmaf(di, a0, b2[0]);
            o1 = fmaf(di, a1, b2[1]);
            o2 = fmaf(di, a2, b2[2]);
            vc = 1.f;
        }
        g = batch[i];
    }
    int g0 = __shfl(g, 0);
    bool uni = __all(g == g0);
    if (uni) {
        for (int off = 32; off; off >>= 1) {
            o0 += __shfl_down(o0, off);
            o1 += __shfl_down(o1, off);
            o2 += __shfl_down(o2, off);
            vc += __shfl_down(vc, off);
        }
        if ((threadIdx.x & 63) == 0 && g0 >= 0) {
            atomicAdd(&pooled[3 * g0],     o0);
            atomicAdd(&pooled[3 * g0 + 1], o1);
            atomicAdd(&pooled[3 * g0 + 2], o2);
            atomicAdd(&cnt[g0], vc);
        }
    } else if (g >= 0 && lane == 0) {
        atomicAdd(&pooled[3 * g],     o0);
        atomicAdd(&pooled[3 * g + 1], o1);
        atomicAdd(&pooled[3 * g + 2], o2);
        atomicAdd(&cnt[g], 1.f);
    }
}

__global__ void k_out(const float* __restrict__ pooled, const float* __restrict__ cnt,
                      float* __restrict__ out, int G) {
    int g = blockIdx.x * blockDim.x + threadIdx.x;
    if (g >= G) return;
    float c = fmaxf(cnt[g], 1.0f);
    float p0 = pooled[3 * g] / c, p1 = pooled[3 * g + 1] / c, p2 = pooled[3 * g + 2] / c;
    float m = fmaxf(p0, fmaxf(p1, p2));
    float s = expf(p0 - m) + expf(p1 - m) + expf(p2 - m);
    float l = logf(s);
    out[3 * g]     = p0 - m - l;
    out[3 * g + 1] = p1 - m - l;
    out[3 * g + 2] = p2 - m - l;
}

// ============ PATH B: fallback (atomic scatter) ============

__global__ void kB_deg(const int* __restrict__ dst, float* __restrict__ deg, int E) {
    int i = blockIdx.x * blockDim.x + threadIdx.x;
    if (i < E) atomicAdd(&deg[dst[i]], 1.0f);
}

__global__ void kB_dinv(float* __restrict__ deg, int n) {
    int i = blockIdx.x * blockDim.x + threadIdx.x;
    if (i < n) deg[i] = rsqrtf(deg[i] + 1.0f);
}

__global__ void kB_agg1(const int* __restrict__ src, const int* __restrict__ dst,
                        const float* __restrict__ dinv, const float* __restrict__ x,
                        float* __restrict__ agg1, int E) {
    int i = blockIdx.x * blockDim.x + threadIdx.x;
    if (i >= E) return;
    int s = src[i], d = dst[i];
    float w = dinv[s] * dinv[d];
    float2 xs = *reinterpret_cast<const float2*>(&x[2 * s]);
    atomicAdd(&agg1[2 * d],     w * xs.x);
    atomicAdd(&agg1[2 * d + 1], w * xs.y);
}

__global__ void kB_z(const float* __restrict__ agg1, const float* __restrict__ x,
                     const float* __restrict__ dinv,
                     const float* __restrict__ W1, const float* __restrict__ b1,
                     const float* __restrict__ W2, float* __restrict__ z, int n) {
    __shared__ float sW1[128], sb1[64], sW2[192];
    for (int t = threadIdx.x; t < 128; t += blockDim.x) sW1[t] = W1[t];
    for (int t = threadIdx.x; t < 64;  t += blockDim.x) sb1[t] = b1[t];
    for (int t = threadIdx.x; t < 192; t += blockDim.x) sW2[t] = W2[t];
    __syncthreads();
    int i = blockIdx.x * blockDim.x + threadIdx.x;
    if (i >= n) return;
    float di = dinv[i], w = di * di;
    float2 xs = *reinterpret_cast<const float2*>(&x[2 * i]);
    float a0 = agg1[2 * i]     + w * xs.x;
    float a1 = agg1[2 * i + 1] + w * xs.y;
    float z0 = 0.f, z1 = 0.f, z2 = 0.f;
#pragma unroll
    for (int j = 0; j < 64; ++j) {
        float h = fmaf(a0, sW1[j], fmaf(a1, sW1[64 + j], sb1[j]));
        h = fmaxf(h, 0.f);
        z0 = fmaf(h, sW2[3 * j],     z0);
        z1 = fmaf(h, sW2[3 * j + 1], z1);
        z2 = fmaf(h, sW2[3 * j + 2], z2);
    }
    z[3 * i] = z0; z[3 * i + 1] = z1; z[3 * i + 2] = z2;
}

__global__ void kB_agg2(const int* __restrict__ src, const int* __restrict__ dst,
                        const float* __restrict__ dinv, const float* __restrict__ z,
                        float* __restrict__ agg2, int E) {
    int i = blockIdx.x * blockDim.x + threadIdx.x;
    if (i >= E) return;
    int s = src[i], d = dst[i];
    float w = dinv[s] * dinv[d];
    atomicAdd(&agg2[3 * d],     w * z[3 * s]);
    atomicAdd(&agg2[3 * d + 1], w * z[3 * s + 1]);
    atomicAdd(&agg2[3 * d + 2], w * z[3 * s + 2]);
}

__global__ void kB_pool(const float* __restrict__ agg2, const float* __restrict__ z,
                        const float* __restrict__ dinv, const float* __restrict__ b2,
                        const int* __restrict__ batch,
                        float* __restrict__ pooled, float* __restrict__ cnt, int n) {
    int i = blockIdx.x * blockDim.x + threadIdx.x;
    if (i >= n) return;
    float di = dinv[i], w = di * di;
    float o0 = agg2[3 * i]     + w * z[3 * i]     + b2[0];
    float o1 = agg2[3 * i + 1] + w * z[3 * i + 1] + b2[1];
    float o2 = agg2[3 * i + 2] + w * z[3 * i + 2] + b2[2];
    int g = batch[i];
    atomicAdd(&pooled[3 * g],     o0);
    atomicAdd(&pooled[3 * g + 1], o1);
    atomicAdd(&pooled[3 * g + 2], o2);
    atomicAdd(&cnt[g], 1.0f);
}

// ============ launch ============

extern "C" void kernel_launch(void* const* d_in, const int* in_sizes, int n_in,
                              void* d_out, int out_size, void* d_ws, size_t ws_size,
                              hipStream_t stream) {
    const float* x     = (const float*)d_in[0];
    const int*   ei    = (const int*)  d_in[1];
    const int*   batch = (const int*)  d_in[2];
    const float* W1    = (const float*)d_in[3];
    const float* b1    = (const float*)d_in[4];
    const float* W2    = (const float*)d_in[5];
    const float* b2    = (const float*)d_in[6];
    float*       out   = (float*)d_out;

    const int n = in_sizes[2];
    const int E = in_sizes[1] / 2;
    const int G = out_size / 3;
    const int* src = ei;
    const int* dst = ei + E;
    const int B = 256;

    const int nbuk  = (n + BUCK - 1) >> SH;
    const int chunk = (E + NBLK - 1) / NBLK;
    const int M     = nbuk * NBLK;
    const int NB2   = (M + SCB - 1) / SCB;

    // Path-A workspace layout (4B units)
    size_t o = 0;
    size_t off_h2   = o; o += M;
    size_t off_rs2  = o; o += M;
    size_t off_bs   = o; o += 1024;
    size_t off_bse  = o; o += 1024;
    size_t off_part = o; o += E;
    size_t off_p2   = o; o += E;
    size_t off_row  = o; o += (size_t)nbuk * BUCK + 1;
    size_t off_dinv = o; o += n;
    size_t off_xw   = o; o += (size_t)2 * n;
    o = (o + 3) & ~(size_t)3;                 // 16B-align zw
    size_t off_zw   = o; o += (size_t)4 * n;
    size_t off_pool = o; o += (size_t)3 * G;
    size_t off_cnt  = o; o += G;
    size_t needA = o * 4;

    if (ws_size >= needA && nbuk <= NBUK_MAX && NB2 <= 1024) {
        int*    h2     = (int*)d_ws + off_h2;
        int*    rs2    = (int*)d_ws + off_rs2;
        int*    bs     = (int*)d_ws + off_bs;
        int*    bse    = (int*)d_ws + off_bse;
        int*    part   = (int*)d_ws + off_part;
        int*    part2  = (int*)d_ws + off_p2;
        int*    row    = (int*)d_ws + off_row;
        float*  dinv   = (float*)d_ws + off_dinv;
        float2* xw     = (float2*)((float*)d_ws + off_xw);
        float4* zw     = (float4*)((float*)d_ws + off_zw);
        float*  pooled = (float*)d_ws + off_pool;
        float*  cnt    = (float*)d_ws + off_cnt;

        hipMemsetAsync(pooled, 0, (size_t)4 * G * 4, stream);  // pooled+cnt contiguous
        k_pcount<<<NBLK, PTH, 0, stream>>>(dst, h2, E, nbuk, chunk);
        k_scanA <<<NB2, SCB, 0, stream>>>(h2, rs2, bs, M);
        k_scanB <<<1, 1024, 0, stream>>>(bs, bse, NB2);
        k_pfill <<<NBLK, PTH, 0, stream>>>(src, dst, rs2, bse, part, E, nbuk, chunk);
        k_prep  <<<nbuk, 512, 0, stream>>>(part, rs2, bse, x, part2, row, dinv, xw, n, nbuk, E);
        k_bz    <<<(4 * n + 255) / 256, 256, 0, stream>>>(part2, row, dinv, xw, W1, b1, W2, zw, n);
        k_bout  <<<(8 * n + 255) / 256, 256, 0, stream>>>(part2, row, dinv, zw, b2, batch, pooled, cnt, n);
        k_out   <<<(G + B - 1) / B, B, 0, stream>>>(pooled, cnt, out, G);
    } else {
        float* ws     = (float*)d_ws;
        float* deg    = ws;
        float* agg1   = deg + n;
        float* agg2   = agg1 + 2 * (size_t)n;
        float* pooled = agg2 + 3 * (size_t)n;
        float* cnt    = pooled + 3 * (size_t)G;
        float* zf     = cnt + G;

        size_t zero_floats = (size_t)6 * n + (size_t)4 * G;
        hipMemsetAsync(ws, 0, zero_floats * sizeof(float), stream);
        kB_deg <<<(E + B - 1) / B, B, 0, stream>>>(dst, deg, E);
        kB_dinv<<<(n + B - 1) / B, B, 0, stream>>>(deg, n);
        kB_agg1<<<(E + B - 1) / B, B, 0, stream>>>(src, dst, deg, x, agg1, E);
        kB_z   <<<(n + B - 1) / B, B, 0, stream>>>(agg1, x, deg, W1, b1, W2, zf, n);
        kB_agg2<<<(E + B - 1) / B, B, 0, stream>>>(src, dst, deg, zf, agg2, E);
        kB_pool<<<(n + B - 1) / B, B, 0, stream>>>(agg2, zf, deg, b2, batch, pooled, cnt, n);
        k_out  <<<(G + B - 1) / B, B, 0, stream>>>(pooled, cnt, out, G);
    }
}

// Round 8
// 147.315 us; speedup vs baseline: 1.1862x; 1.1862x over previous
//
#include <hip/hip_runtime.h>

#define NBLK 1024         // partition blocks
#define PTH  512          // pcount/pfill threads
#define SH   9
#define BUCK 512          // nodes per bucket = 1<<SH
#define NBUK_MAX 512
#define SCB  512          // scanA block width
#define PREP_CAP 10240    // max staged edges per bucket in k_prep (40KB LDS)

// ============ PATH A: bucket sort -> exact CSR -> 4-lane unrolled gathers ============

__global__ void __launch_bounds__(PTH) k_pcount(const int* __restrict__ dst,
                                                int* __restrict__ hist2d,
                                                int E, int nbuk, int chunk) {
    __shared__ int h[NBUK_MAX];
    for (int t = threadIdx.x; t < nbuk; t += PTH) h[t] = 0;
    __syncthreads();
    int beg = blockIdx.x * chunk, end = min(beg + chunk, E);
    for (int i = beg + threadIdx.x; i < end; i += PTH)
        atomicAdd(&h[dst[i] >> SH], 1);
    __syncthreads();
    for (int t = threadIdx.x; t < nbuk; t += PTH)
        hist2d[t * NBLK + blockIdx.x] = h[t];
}

__global__ void __launch_bounds__(SCB) k_scanA(const int* __restrict__ in,
                                               int* __restrict__ outp,
                                               int* __restrict__ bsum, int M) {
    __shared__ int s[SCB];
    int t = threadIdx.x, i = blockIdx.x * SCB + t;
    int h = (i < M) ? in[i] : 0;
    s[t] = h; __syncthreads();
    for (int off = 1; off < SCB; off <<= 1) {
        int v = (t >= off) ? s[t - off] : 0;
        __syncthreads();
        s[t] += v;
        __syncthreads();
    }
    if (i < M) outp[i] = s[t] - h;
    if (t == SCB - 1) bsum[blockIdx.x] = s[SCB - 1];
}

__global__ void k_scanB(const int* __restrict__ bsum, int* __restrict__ bsum_ex, int NB) {
    __shared__ int s[1024];
    int t = threadIdx.x;
    int v = (t < NB) ? bsum[t] : 0;
    s[t] = v; __syncthreads();
    for (int off = 1; off < 1024; off <<= 1) {
        int u = (t >= off) ? s[t - off] : 0;
        __syncthreads();
        s[t] += u;
        __syncthreads();
    }
    if (t < NB) bsum_ex[t] = s[t] - v;
}

__device__ __forceinline__ int scan_off(const int* rs2, const int* bse, int j) {
    return rs2[j] + bse[j >> 9];          // SCB=512
}

__global__ void __launch_bounds__(PTH) k_pfill(const int* __restrict__ src,
                                               const int* __restrict__ dst,
                                               const int* __restrict__ rs2,
                                               const int* __restrict__ bse,
                                               int* __restrict__ part,
                                               int E, int nbuk, int chunk) {
    __shared__ int cur[NBUK_MAX];
    for (int t = threadIdx.x; t < nbuk; t += PTH)
        cur[t] = scan_off(rs2, bse, t * NBLK + blockIdx.x);
    __syncthreads();
    int beg = blockIdx.x * chunk, end = min(beg + chunk, E);
    for (int i = beg + threadIdx.x; i < end; i += PTH) {
        int d = dst[i];
        int pos = atomicAdd(&cur[d >> SH], 1);     // LDS atomic
        part[pos] = (src[i] << SH) | (d & (BUCK - 1));
    }
}

// per bucket: hist -> scan -> LDS-staged scatter into dst-sorted part2 (coalesced
// global write); also rowstart (absolute), dinv, xw = dinv*x
__global__ void __launch_bounds__(512) k_prep(
        const int* __restrict__ part, const int* __restrict__ rs2,
        const int* __restrict__ bse, const float* __restrict__ x,
        int* __restrict__ part2, int* __restrict__ rowstart,
        float* __restrict__ dinv, float2* __restrict__ xw,
        int n, int nbuk, int E) {
    __shared__ int hist[BUCK];
    __shared__ int s[BUCK];
    __shared__ int cur[BUCK];
    __shared__ int outbuf[PREP_CAP];
    int t = threadIdx.x, b = blockIdx.x;
    hist[t] = 0;
    __syncthreads();
    int beg = scan_off(rs2, bse, b * NBLK);
    int end = (b + 1 < nbuk) ? scan_off(rs2, bse, (b + 1) * NBLK) : E;
    for (int i = beg + t; i < end; i += 512)
        atomicAdd(&hist[part[i] & (BUCK - 1)], 1);
    __syncthreads();
    s[t] = hist[t];
    __syncthreads();
    for (int d = 1; d < 512; d <<= 1) {
        int v = (t >= d) ? s[t - d] : 0;
        __syncthreads();
        s[t] += v;
        __syncthreads();
    }
    int excl = s[t] - hist[t];
    cur[t] = beg + excl;
    int node = (b << SH) + t;
    rowstart[node] = beg + excl;
    if (node < n) {
        float di = rsqrtf((float)hist[t] + 1.0f);
        dinv[node] = di;
        float2 xs = *reinterpret_cast<const float2*>(&x[2 * node]);
        xw[node] = make_float2(di * xs.x, di * xs.y);
    }
    __syncthreads();
    int cnt = end - beg;
    bool staged = (cnt <= PREP_CAP);
    if (staged) {
        for (int i = beg + t; i < end; i += 512) {
            int e = part[i];
            int p = atomicAdd(&cur[e & (BUCK - 1)], 1);
            outbuf[p - beg] = e >> SH;
        }
        __syncthreads();
        for (int i = t; i < cnt; i += 512)
            part2[beg + i] = outbuf[i];             // coalesced
    } else {
        for (int i = beg + t; i < end; i += 512) {
            int e = part[i];
            int p = atomicAdd(&cur[e & (BUCK - 1)], 1);
            part2[p] = e >> SH;
        }
    }
}

// layer-1: 4 lanes/node, 2-way unrolled independent gathers + butterfly;
// MLP split 16 hidden units/lane
__global__ void __launch_bounds__(256) k_bz(
        const int* __restrict__ part2, const int* __restrict__ rowstart,
        const float* __restrict__ dinv, const float2* __restrict__ xw,
        const float* __restrict__ W1, const float* __restrict__ b1,
        const float* __restrict__ W2, float4* __restrict__ zw, int n) {
    __shared__ float sW1[128], sb1[64], sW2[192];
    for (int t = threadIdx.x; t < 128; t += 256) sW1[t] = W1[t];
    for (int t = threadIdx.x; t < 64;  t += 256) sb1[t] = b1[t];
    for (int t = threadIdx.x; t < 192; t += 256) sW2[t] = W2[t];
    __syncthreads();
    int tid = blockIdx.x * 256 + threadIdx.x;
    int i = tid >> 2, lane = tid & 3;
    if (i >= n) return;
    int beg = rowstart[i], end = rowstart[i + 1];
    float a0 = 0.f, a1 = 0.f;
    int e = beg + lane;
    for (; e + 4 < end; e += 8) {                  // pair of independent chains
        int s0 = part2[e];
        int s1 = part2[e + 4];
        float2 v0 = xw[s0];
        float2 v1 = xw[s1];
        a0 += v0.x + v1.x;
        a1 += v0.y + v1.y;
    }
    if (e < end) {
        float2 v = xw[part2[e]];
        a0 += v.x; a1 += v.y;
    }
    if (lane == 0) {                               // self-loop term once
        float2 self = xw[i];
        a0 += self.x; a1 += self.y;
    }
    a0 += __shfl_xor(a0, 1); a0 += __shfl_xor(a0, 2);
    a1 += __shfl_xor(a1, 1); a1 += __shfl_xor(a1, 2);
    float di = dinv[i];
    a0 *= di; a1 *= di;
    float z0 = 0.f, z1 = 0.f, z2 = 0.f;
    int j0 = lane << 4;
#pragma unroll
    for (int jj = 0; jj < 16; ++jj) {
        int j = j0 + jj;
        float h = fmaf(a0, sW1[j], fmaf(a1, sW1[64 + j], sb1[j]));
        h = fmaxf(h, 0.f);
        z0 = fmaf(h, sW2[3 * j],     z0);
        z1 = fmaf(h, sW2[3 * j + 1], z1);
        z2 = fmaf(h, sW2[3 * j + 2], z2);
    }
    z0 += __shfl_xor(z0, 1); z0 += __shfl_xor(z0, 2);
    z1 += __shfl_xor(z1, 1); z1 += __shfl_xor(z1, 2);
    z2 += __shfl_xor(z2, 1); z2 += __shfl_xor(z2, 2);
    if (lane == 0)
        zw[i] = make_float4(di * z0, di * z1, di * z2, 0.f);   // pre-scaled payload
}

// layer-2: 4 lanes/node, 2-way unrolled independent gathers + butterfly;
// epilogue + sorted-batch wave pooling
__global__ void __launch_bounds__(256) k_bout(
        const int* __restrict__ part2, const int* __restrict__ rowstart,
        const float* __restrict__ dinv, const float4* __restrict__ zw,
        const float* __restrict__ b2, const int* __restrict__ batch,
        float* __restrict__ pooled, float* __restrict__ cnt, int n) {
    int tid = blockIdx.x * 256 + threadIdx.x;
    int i = tid >> 2, lane = tid & 3;
    float o0 = 0.f, o1 = 0.f, o2 = 0.f, vc = 0.f;
    int g = -1;
    if (i < n) {
        int beg = rowstart[i], end = rowstart[i + 1];
        float a0 = 0.f, a1 = 0.f, a2 = 0.f;
        int e = beg + lane;
        for (; e + 4 < end; e += 8) {              // pair of independent chains
            int s0 = part2[e];
            int s1 = part2[e + 4];
            float4 v0 = zw[s0];
            float4 v1 = zw[s1];
            a0 += v0.x + v1.x;
            a1 += v0.y + v1.y;
            a2 += v0.z + v1.z;
        }
        if (e < end) {
            float4 v = zw[part2[e]];
            a0 += v.x; a1 += v.y; a2 += v.z;
        }
        if (lane == 0) {
            float4 self = zw[i];
            a0 += self.x; a1 += self.y; a2 += self.z;
        }
        a0 += __shfl_xor(a0, 1); a0 += __shfl_xor(a0, 2);
        a1 += __shfl_xor(a1, 1); a1 += __shfl_xor(a1, 2);
        a2 += __shfl_xor(a2, 1); a2 += __shfl_xor(a2, 2);
        if (lane == 0) {                            // one contribution per node
            float di = dinv[i];
            o0 = fmaf(di, a0, b2[0]);
            o1 = fmaf(di, a1, b2[1]);
            o2 = fmaf(di, a2, b2[2]);
            vc = 1.f;
        }
        g = batch[i];
    }
    int g0 = __shfl(g, 0);
    bool uni = __all(g == g0);
    if (uni) {
        for (int off = 32; off; off >>= 1) {
            o0 += __shfl_down(o0, off);
            o1 += __shfl_down(o1, off);
            o2 += __shfl_down(o2, off);
            vc += __shfl_down(vc, off);
        }
        if ((threadIdx.x & 63) == 0 && g0 >= 0) {
            atomicAdd(&pooled[3 * g0],     o0);
            atomicAdd(&pooled[3 * g0 + 1], o1);
            atomicAdd(&pooled[3 * g0 + 2], o2);
            atomicAdd(&cnt[g0], vc);
        }
    } else if (g >= 0 && lane == 0) {
        atomicAdd(&pooled[3 * g],     o0);
        atomicAdd(&pooled[3 * g + 1], o1);
        atomicAdd(&pooled[3 * g + 2], o2);
        atomicAdd(&cnt[g], 1.f);
    }
}

__global__ void k_out(const float* __restrict__ pooled, const float* __restrict__ cnt,
                      float* __restrict__ out, int G) {
    int g = blockIdx.x * blockDim.x + threadIdx.x;
    if (g >= G) return;
    float c = fmaxf(cnt[g], 1.0f);
    float p0 = pooled[3 * g] / c, p1 = pooled[3 * g + 1] / c, p2 = pooled[3 * g + 2] / c;
    float m = fmaxf(p0, fmaxf(p1, p2));
    float s = expf(p0 - m) + expf(p1 - m) + expf(p2 - m);
    float l = logf(s);
    out[3 * g]     = p0 - m - l;
    out[3 * g + 1] = p1 - m - l;
    out[3 * g + 2] = p2 - m - l;
}

// ============ PATH B: fallback (atomic scatter) ============

__global__ void kB_deg(const int* __restrict__ dst, float* __restrict__ deg, int E) {
    int i = blockIdx.x * blockDim.x + threadIdx.x;
    if (i < E) atomicAdd(&deg[dst[i]], 1.0f);
}

__global__ void kB_dinv(float* __restrict__ deg, int n) {
    int i = blockIdx.x * blockDim.x + threadIdx.x;
    if (i < n) deg[i] = rsqrtf(deg[i] + 1.0f);
}

__global__ void kB_agg1(const int* __restrict__ src, const int* __restrict__ dst,
                        const float* __restrict__ dinv, const float* __restrict__ x,
                        float* __restrict__ agg1, int E) {
    int i = blockIdx.x * blockDim.x + threadIdx.x;
    if (i >= E) return;
    int s = src[i], d = dst[i];
    float w = dinv[s] * dinv[d];
    float2 xs = *reinterpret_cast<const float2*>(&x[2 * s]);
    atomicAdd(&agg1[2 * d],     w * xs.x);
    atomicAdd(&agg1[2 * d + 1], w * xs.y);
}

__global__ void kB_z(const float* __restrict__ agg1, const float* __restrict__ x,
                     const float* __restrict__ dinv,
                     const float* __restrict__ W1, const float* __restrict__ b1,
                     const float* __restrict__ W2, float* __restrict__ z, int n) {
    __shared__ float sW1[128], sb1[64], sW2[192];
    for (int t = threadIdx.x; t < 128; t += blockDim.x) sW1[t] = W1[t];
    for (int t = threadIdx.x; t < 64;  t += blockDim.x) sb1[t] = b1[t];
    for (int t = threadIdx.x; t < 192; t += blockDim.x) sW2[t] = W2[t];
    __syncthreads();
    int i = blockIdx.x * blockDim.x + threadIdx.x;
    if (i >= n) return;
    float di = dinv[i], w = di * di;
    float2 xs = *reinterpret_cast<const float2*>(&x[2 * i]);
    float a0 = agg1[2 * i]     + w * xs.x;
    float a1 = agg1[2 * i + 1] + w * xs.y;
    float z0 = 0.f, z1 = 0.f, z2 = 0.f;
#pragma unroll
    for (int j = 0; j < 64; ++j) {
        float h = fmaf(a0, sW1[j], fmaf(a1, sW1[64 + j], sb1[j]));
        h = fmaxf(h, 0.f);
        z0 = fmaf(h, sW2[3 * j],     z0);
        z1 = fmaf(h, sW2[3 * j + 1], z1);
        z2 = fmaf(h, sW2[3 * j + 2], z2);
    }
    z[3 * i] = z0; z[3 * i + 1] = z1; z[3 * i + 2] = z2;
}

__global__ void kB_agg2(const int* __restrict__ src, const int* __restrict__ dst,
                        const float* __restrict__ dinv, const float* __restrict__ z,
                        float* __restrict__ agg2, int E) {
    int i = blockIdx.x * blockDim.x + threadIdx.x;
    if (i >= E) return;
    int s = src[i], d = dst[i];
    float w = dinv[s] * dinv[d];
    atomicAdd(&agg2[3 * d],     w * z[3 * s]);
    atomicAdd(&agg2[3 * d + 1], w * z[3 * s + 1]);
    atomicAdd(&agg2[3 * d + 2], w * z[3 * s + 2]);
}

__global__ void kB_pool(const float* __restrict__ agg2, const float* __restrict__ z,
                        const float* __restrict__ dinv, const float* __restrict__ b2,
                        const int* __restrict__ batch,
                        float* __restrict__ pooled, float* __restrict__ cnt, int n) {
    int i = blockIdx.x * blockDim.x + threadIdx.x;
    if (i >= n) return;
    float di = dinv[i], w = di * di;
    float o0 = agg2[3 * i]     + w * z[3 * i]     + b2[0];
    float o1 = agg2[3 * i + 1] + w * z[3 * i + 1] + b2[1];
    float o2 = agg2[3 * i + 2] + w * z[3 * i + 2] + b2[2];
    int g = batch[i];
    atomicAdd(&pooled[3 * g],     o0);
    atomicAdd(&pooled[3 * g + 1], o1);
    atomicAdd(&pooled[3 * g + 2], o2);
    atomicAdd(&cnt[g], 1.0f);
}

// ============ launch ============

extern "C" void kernel_launch(void* const* d_in, const int* in_sizes, int n_in,
                              void* d_out, int out_size, void* d_ws, size_t ws_size,
                              hipStream_t stream) {
    const float* x     = (const float*)d_in[0];
    const int*   ei    = (const int*)  d_in[1];
    const int*   batch = (const int*)  d_in[2];
    const float* W1    = (const float*)d_in[3];
    const float* b1    = (const float*)d_in[4];
    const float* W2    = (const float*)d_in[5];
    const float* b2    = (const float*)d_in[6];
    float*       out   = (float*)d_out;

    const int n = in_sizes[2];
    const int E = in_sizes[1] / 2;
    const int G = out_size / 3;
    const int* src = ei;
    const int* dst = ei + E;
    const int B = 256;

    const int nbuk  = (n + BUCK - 1) >> SH;
    const int chunk = (E + NBLK - 1) / NBLK;
    const int M     = nbuk * NBLK;
    const int NB2   = (M + SCB - 1) / SCB;

    // Path-A workspace layout (4B units)
    size_t o = 0;
    size_t off_h2   = o; o += M;
    size_t off_rs2  = o; o += M;
    size_t off_bs   = o; o += 1024;
    size_t off_bse  = o; o += 1024;
    size_t off_part = o; o += E;
    size_t off_p2   = o; o += E;
    size_t off_row  = o; o += (size_t)nbuk * BUCK + 1;
    size_t off_dinv = o; o += n;
    size_t off_xw   = o; o += (size_t)2 * n;
    o = (o + 3) & ~(size_t)3;                 // 16B-align zw
    size_t off_zw   = o; o += (size_t)4 * n;
    size_t off_pool = o; o += (size_t)3 * G;
    size_t off_cnt  = o; o += G;
    size_t needA = o * 4;

    if (ws_size >= needA && nbuk <= NBUK_MAX && NB2 <= 1024) {
        int*    h2     = (int*)d_ws + off_h2;
        int*    rs2    = (int*)d_ws + off_rs2;
        int*    bs     = (int*)d_ws + off_bs;
        int*    bse    = (int*)d_ws + off_bse;
        int*    part   = (int*)d_ws + off_part;
        int*    part2  = (int*)d_ws + off_p2;
        int*    row    = (int*)d_ws + off_row;
        float*  dinv   = (float*)d_ws + off_dinv;
        float2* xw     = (float2*)((float*)d_ws + off_xw);
        float4* zw     = (float4*)((float*)d_ws + off_zw);
        float*  pooled = (float*)d_ws + off_pool;
        float*  cnt    = (float*)d_ws + off_cnt;

        hipMemsetAsync(pooled, 0, (size_t)4 * G * 4, stream);  // pooled+cnt contiguous
        k_pcount<<<NBLK, PTH, 0, stream>>>(dst, h2, E, nbuk, chunk);
        k_scanA <<<NB2, SCB, 0, stream>>>(h2, rs2, bs, M);
        k_scanB <<<1, 1024, 0, stream>>>(bs, bse, NB2);
        k_pfill <<<NBLK, PTH, 0, stream>>>(src, dst, rs2, bse, part, E, nbuk, chunk);
        k_prep  <<<nbuk, 512, 0, stream>>>(part, rs2, bse, x, part2, row, dinv, xw, n, nbuk, E);
        k_bz    <<<(4 * n + 255) / 256, 256, 0, stream>>>(part2, row, dinv, xw, W1, b1, W2, zw, n);
        k_bout  <<<(4 * n + 255) / 256, 256, 0, stream>>>(part2, row, dinv, zw, b2, batch, pooled, cnt, n);
        k_out   <<<(G + B - 1) / B, B, 0, stream>>>(pooled, cnt, out, G);
    } else {
        float* ws     = (float*)d_ws;
        float* deg    = ws;
        float* agg1   = deg + n;
        float* agg2   = agg1 + 2 * (size_t)n;
        float* pooled = agg2 + 3 * (size_t)n;
        float* cnt    = pooled + 3 * (size_t)G;
        float* zf     = cnt + G;

        size_t zero_floats = (size_t)6 * n + (size_t)4 * G;
        hipMemsetAsync(ws, 0, zero_floats * sizeof(float), stream);
        kB_deg <<<(E + B - 1) / B, B, 0, stream>>>(dst, deg, E);
        kB_dinv<<<(n + B - 1) / B, B, 0, stream>>>(deg, n);
        kB_agg1<<<(E + B - 1) / B, B, 0, stream>>>(src, dst, deg, x, agg1, E);
        kB_z   <<<(n + B - 1) / B, B, 0, stream>>>(agg1, x, deg, W1, b1, W2, zf, n);
        kB_agg2<<<(E + B - 1) / B, B, 0, stream>>>(src, dst, deg, zf, agg2, E);
        kB_pool<<<(n + B - 1) / B, B, 0, stream>>>(agg2, zf, deg, b2, batch, pooled, cnt, n);
        k_out  <<<(G + B - 1) / B, B, 0, stream>>>(pooled, cnt, out, G);
    }
}

// Round 9
// 132.321 us; speedup vs baseline: 1.3206x; 1.1133x over previous
//
#include <hip/hip_runtime.h>
#include <hip/hip_fp16.h>

#define NBLK 1024         // partition blocks
#define PTH  512          // pcount/pfill threads
#define SH   9
#define BUCK 512          // nodes per bucket = 1<<SH
#define NBUK_MAX 512
#define SCB  512          // scanA block width
#define PREP_CAP 10240    // max staged edges per bucket in k_prep (40KB LDS)
#define TILE 4096         // pfill per-tile staged edges (16KB LDS)

__device__ __forceinline__ unsigned pack2(float a, float b) {
    __half ha = __float2half_rn(a), hb = __float2half_rn(b);
    unsigned short ua = *reinterpret_cast<unsigned short*>(&ha);
    unsigned short ub = *reinterpret_cast<unsigned short*>(&hb);
    return ((unsigned)ub << 16) | ua;
}
__device__ __forceinline__ float2 unpack2(unsigned u) {
    unsigned short ua = (unsigned short)(u & 0xffff), ub = (unsigned short)(u >> 16);
    __half ha = *reinterpret_cast<__half*>(&ua), hb = *reinterpret_cast<__half*>(&ub);
    return make_float2(__half2float(ha), __half2float(hb));
}

// ============ PATH A: bucket sort -> exact CSR -> 4-lane gathers (f16 payloads) ============

// Pass A: per-block LDS histogram of dst buckets (int4-vectorized)
__global__ void __launch_bounds__(PTH) k_pcount(const int* __restrict__ dst,
                                                int* __restrict__ hist2d,
                                                int E, int nbuk, int chunk) {
    __shared__ int h[NBUK_MAX];
    for (int t = threadIdx.x; t < nbuk; t += PTH) h[t] = 0;
    __syncthreads();
    int beg = blockIdx.x * chunk, end = min(beg + chunk, E);   // beg is 4-aligned (chunk%4==0)
    int len = end - beg;
    if (len > 0) {
        int nq = len >> 2;
        for (int q = threadIdx.x; q < nq; q += PTH) {
            int4 d4 = *reinterpret_cast<const int4*>(&dst[beg + (q << 2)]);
            atomicAdd(&h[d4.x >> SH], 1);
            atomicAdd(&h[d4.y >> SH], 1);
            atomicAdd(&h[d4.z >> SH], 1);
            atomicAdd(&h[d4.w >> SH], 1);
        }
        for (int i = beg + (nq << 2) + threadIdx.x; i < end; i += PTH)
            atomicAdd(&h[dst[i] >> SH], 1);
    }
    __syncthreads();
    for (int t = threadIdx.x; t < nbuk; t += PTH)
        hist2d[t * NBLK + blockIdx.x] = h[t];
}

__global__ void __launch_bounds__(SCB) k_scanA(const int* __restrict__ in,
                                               int* __restrict__ outp,
                                               int* __restrict__ bsum, int M) {
    __shared__ int s[SCB];
    int t = threadIdx.x, i = blockIdx.x * SCB + t;
    int h = (i < M) ? in[i] : 0;
    s[t] = h; __syncthreads();
    for (int off = 1; off < SCB; off <<= 1) {
        int v = (t >= off) ? s[t - off] : 0;
        __syncthreads();
        s[t] += v;
        __syncthreads();
    }
    if (i < M) outp[i] = s[t] - h;
    if (t == SCB - 1) bsum[blockIdx.x] = s[SCB - 1];
}

__global__ void k_scanB(const int* __restrict__ bsum, int* __restrict__ bsum_ex, int NB) {
    __shared__ int s[1024];
    int t = threadIdx.x;
    int v = (t < NB) ? bsum[t] : 0;
    s[t] = v; __syncthreads();
    for (int off = 1; off < 1024; off <<= 1) {
        int u = (t >= off) ? s[t - off] : 0;
        __syncthreads();
        s[t] += u;
        __syncthreads();
    }
    if (t < NB) bsum_ex[t] = s[t] - v;
}

__device__ __forceinline__ int scan_off(const int* rs2, const int* bse, int j) {
    return rs2[j] + bse[j >> 9];          // SCB=512
}

// Pass B: chunk-local LDS counting sort -> COALESCED writes of bucket runs
__global__ void __launch_bounds__(PTH) k_pfill(const int* __restrict__ src,
                                               const int* __restrict__ dst,
                                               const int* __restrict__ rs2,
                                               const int* __restrict__ bse,
                                               int* __restrict__ part,
                                               int E, int nbuk, int chunk) {
    __shared__ int gcur[NBUK_MAX];     // block's global cursor per bucket
    __shared__ int hist[NBUK_MAX];
    __shared__ int scn[NBUK_MAX];      // inclusive scan of hist
    __shared__ int lcur[NBUK_MAX];     // tile-local cursors
    __shared__ int lout[TILE];         // tile-local bucket-sorted packed edges
    int t = threadIdx.x, b = blockIdx.x;
    for (int u = t; u < nbuk; u += PTH)
        gcur[u] = scan_off(rs2, bse, u * NBLK + b);
    int beg = b * chunk, end = min(beg + chunk, E);
    for (int tb = beg; tb < end; tb += TILE) {
        int te = min(tb + TILE, end), cnt = te - tb;
        for (int u = t; u < nbuk; u += PTH) hist[u] = 0;
        __syncthreads();
        for (int i = tb + t; i < te; i += PTH)
            atomicAdd(&hist[dst[i] >> SH], 1);
        __syncthreads();
        int v = (t < nbuk) ? hist[t] : 0;
        scn[t] = v; __syncthreads();
        for (int off = 1; off < PTH; off <<= 1) {
            int u = (t >= off) ? scn[t - off] : 0;
            __syncthreads();
            scn[t] += u;
            __syncthreads();
        }
        if (t < nbuk) lcur[t] = scn[t] - hist[t];  // exclusive
        __syncthreads();
        for (int i = tb + t; i < te; i += PTH) {
            int d = dst[i];
            int p = atomicAdd(&lcur[d >> SH], 1);
            lout[p] = (src[i] << SH) | (d & (BUCK - 1));
        }
        __syncthreads();
        // coalesced copy-out: position j -> bucket via binary search on scn
        for (int j = t; j < cnt; j += PTH) {
            int lo = 0, hi = nbuk - 1;
            while (lo < hi) { int mid = (lo + hi) >> 1; if (scn[mid] > j) hi = mid; else lo = mid + 1; }
            int excl = scn[lo] - hist[lo];
            part[gcur[lo] + (j - excl)] = lout[j];
        }
        __syncthreads();
        for (int u = t; u < nbuk; u += PTH) gcur[u] += hist[u];
        __syncthreads();
    }
}

// per bucket: hist -> scan -> LDS-staged scatter into dst-sorted part2;
// rowstart, dinv, xw = half2(dinv*x)
__global__ void __launch_bounds__(512) k_prep(
        const int* __restrict__ part, const int* __restrict__ rs2,
        const int* __restrict__ bse, const float* __restrict__ x,
        int* __restrict__ part2, int* __restrict__ rowstart,
        float* __restrict__ dinv, unsigned* __restrict__ xw,
        int n, int nbuk, int E) {
    __shared__ int hist[BUCK];
    __shared__ int s[BUCK];
    __shared__ int cur[BUCK];
    __shared__ int outbuf[PREP_CAP];
    int t = threadIdx.x, b = blockIdx.x;
    hist[t] = 0;
    __syncthreads();
    int beg = scan_off(rs2, bse, b * NBLK);
    int end = (b + 1 < nbuk) ? scan_off(rs2, bse, (b + 1) * NBLK) : E;
    // vectorized hist pass
    int ab = (beg + 3) & ~3; if (ab > end) ab = end;
    int tstart = ab + ((end - ab) & ~3);
    for (int i = beg + t; i < ab; i += 512)
        atomicAdd(&hist[part[i] & (BUCK - 1)], 1);
    for (int i = ab + t * 4; i + 3 < end; i += 512 * 4) {
        int4 e4 = *reinterpret_cast<const int4*>(&part[i]);
        atomicAdd(&hist[e4.x & (BUCK - 1)], 1);
        atomicAdd(&hist[e4.y & (BUCK - 1)], 1);
        atomicAdd(&hist[e4.z & (BUCK - 1)], 1);
        atomicAdd(&hist[e4.w & (BUCK - 1)], 1);
    }
    for (int i = tstart + t; i < end; i += 512)
        atomicAdd(&hist[part[i] & (BUCK - 1)], 1);
    __syncthreads();
    s[t] = hist[t];
    __syncthreads();
    for (int d = 1; d < 512; d <<= 1) {
        int v = (t >= d) ? s[t - d] : 0;
        __syncthreads();
        s[t] += v;
        __syncthreads();
    }
    int excl = s[t] - hist[t];
    cur[t] = excl;                       // tile-local (bucket-local) cursor
    int node = (b << SH) + t;
    rowstart[node] = beg + excl;
    if (node < n) {
        float di = rsqrtf((float)hist[t] + 1.0f);
        dinv[node] = di;
        float2 xs = *reinterpret_cast<const float2*>(&x[2 * node]);
        xw[node] = pack2(di * xs.x, di * xs.y);
    }
    __syncthreads();
    int cnt = end - beg;
    bool staged = (cnt <= PREP_CAP);
    if (staged) {
        for (int i = beg + t; i < end; i += 512) {
            int e = part[i];
            int p = atomicAdd(&cur[e & (BUCK - 1)], 1);
            outbuf[p] = e >> SH;
        }
        __syncthreads();
        for (int i = t; i < cnt; i += 512)
            part2[beg + i] = outbuf[i];             // coalesced
    } else {
        for (int i = beg + t; i < end; i += 512) {
            int e = part[i];
            int p = atomicAdd(&cur[e & (BUCK - 1)], 1);
            part2[beg + p] = e >> SH;
        }
    }
}

// layer-1: 4 lanes/node, unrolled 4B half2 gathers + butterfly; MLP 16 hidden/lane
__global__ void __launch_bounds__(256) k_bz(
        const int* __restrict__ part2, const int* __restrict__ rowstart,
        const float* __restrict__ dinv, const unsigned* __restrict__ xw,
        const float* __restrict__ W1, const float* __restrict__ b1,
        const float* __restrict__ W2, uint2* __restrict__ zw, int n) {
    __shared__ float sW1[128], sb1[64], sW2[192];
    for (int t = threadIdx.x; t < 128; t += 256) sW1[t] = W1[t];
    for (int t = threadIdx.x; t < 64;  t += 256) sb1[t] = b1[t];
    for (int t = threadIdx.x; t < 192; t += 256) sW2[t] = W2[t];
    __syncthreads();
    int tid = blockIdx.x * 256 + threadIdx.x;
    int i = tid >> 2, lane = tid & 3;
    if (i >= n) return;
    int beg = rowstart[i], end = rowstart[i + 1];
    float a0 = 0.f, a1 = 0.f;
    int e = beg + lane;
    for (; e + 4 < end; e += 8) {
        int s0 = part2[e];
        int s1 = part2[e + 4];
        float2 v0 = unpack2(xw[s0]);
        float2 v1 = unpack2(xw[s1]);
        a0 += v0.x + v1.x;
        a1 += v0.y + v1.y;
    }
    if (e < end) {
        float2 v = unpack2(xw[part2[e]]);
        a0 += v.x; a1 += v.y;
    }
    if (lane == 0) {
        float2 self = unpack2(xw[i]);
        a0 += self.x; a1 += self.y;
    }
    a0 += __shfl_xor(a0, 1); a0 += __shfl_xor(a0, 2);
    a1 += __shfl_xor(a1, 1); a1 += __shfl_xor(a1, 2);
    float di = dinv[i];
    a0 *= di; a1 *= di;
    float z0 = 0.f, z1 = 0.f, z2 = 0.f;
    int j0 = lane << 4;
#pragma unroll
    for (int jj = 0; jj < 16; ++jj) {
        int j = j0 + jj;
        float h = fmaf(a0, sW1[j], fmaf(a1, sW1[64 + j], sb1[j]));
        h = fmaxf(h, 0.f);
        z0 = fmaf(h, sW2[3 * j],     z0);
        z1 = fmaf(h, sW2[3 * j + 1], z1);
        z2 = fmaf(h, sW2[3 * j + 2], z2);
    }
    z0 += __shfl_xor(z0, 1); z0 += __shfl_xor(z0, 2);
    z1 += __shfl_xor(z1, 1); z1 += __shfl_xor(z1, 2);
    z2 += __shfl_xor(z2, 1); z2 += __shfl_xor(z2, 2);
    if (lane == 0)
        zw[i] = make_uint2(pack2(di * z0, di * z1), pack2(di * z2, 0.f));
}

// layer-2: 4 lanes/node, unrolled 8B gathers + butterfly; epilogue + wave pooling
__global__ void __launch_bounds__(256) k_bout(
        const int* __restrict__ part2, const int* __restrict__ rowstart,
        const float* __restrict__ dinv, const uint2* __restrict__ zw,
        const float* __restrict__ b2, const int* __restrict__ batch,
        float* __restrict__ pooled, float* __restrict__ cnt, int n) {
    int tid = blockIdx.x * 256 + threadIdx.x;
    int i = tid >> 2, lane = tid & 3;
    float o0 = 0.f, o1 = 0.f, o2 = 0.f, vc = 0.f;
    int g = -1;
    if (i < n) {
        int beg = rowstart[i], end = rowstart[i + 1];
        float a0 = 0.f, a1 = 0.f, a2 = 0.f;
        int e = beg + lane;
        for (; e + 4 < end; e += 8) {
            int s0 = part2[e];
            int s1 = part2[e + 4];
            uint2 u0 = zw[s0];
            uint2 u1 = zw[s1];
            float2 p0 = unpack2(u0.x), p1 = unpack2(u1.x);
            a0 += p0.x + p1.x;
            a1 += p0.y + p1.y;
            a2 += unpack2(u0.y).x + unpack2(u1.y).x;
        }
        if (e < end) {
            uint2 u = zw[part2[e]];
            float2 p = unpack2(u.x);
            a0 += p.x; a1 += p.y; a2 += unpack2(u.y).x;
        }
        if (lane == 0) {
            uint2 u = zw[i];
            float2 p = unpack2(u.x);
            a0 += p.x; a1 += p.y; a2 += unpack2(u.y).x;
        }
        a0 += __shfl_xor(a0, 1); a0 += __shfl_xor(a0, 2);
        a1 += __shfl_xor(a1, 1); a1 += __shfl_xor(a1, 2);
        a2 += __shfl_xor(a2, 1); a2 += __shfl_xor(a2, 2);
        if (lane == 0) {
            float di = dinv[i];
            o0 = fmaf(di, a0, b2[0]);
            o1 = fmaf(di, a1, b2[1]);
            o2 = fmaf(di, a2, b2[2]);
            vc = 1.f;
        }
        g = batch[i];
    }
    int g0 = __shfl(g, 0);
    bool uni = __all(g == g0);
    if (uni) {
        for (int off = 32; off; off >>= 1) {
            o0 += __shfl_down(o0, off);
            o1 += __shfl_down(o1, off);
            o2 += __shfl_down(o2, off);
            vc += __shfl_down(vc, off);
        }
        if ((threadIdx.x & 63) == 0 && g0 >= 0) {
            atomicAdd(&pooled[3 * g0],     o0);
            atomicAdd(&pooled[3 * g0 + 1], o1);
            atomicAdd(&pooled[3 * g0 + 2], o2);
            atomicAdd(&cnt[g0], vc);
        }
    } else if (g >= 0 && lane == 0) {
        atomicAdd(&pooled[3 * g],     o0);
        atomicAdd(&pooled[3 * g + 1], o1);
        atomicAdd(&pooled[3 * g + 2], o2);
        atomicAdd(&cnt[g], 1.f);
    }
}

__global__ void k_out(const float* __restrict__ pooled, const float* __restrict__ cnt,
                      float* __restrict__ out, int G) {
    int g = blockIdx.x * blockDim.x + threadIdx.x;
    if (g >= G) return;
    float c = fmaxf(cnt[g], 1.0f);
    float p0 = pooled[3 * g] / c, p1 = pooled[3 * g + 1] / c, p2 = pooled[3 * g + 2] / c;
    float m = fmaxf(p0, fmaxf(p1, p2));
    float s = expf(p0 - m) + expf(p1 - m) + expf(p2 - m);
    float l = logf(s);
    out[3 * g]     = p0 - m - l;
    out[3 * g + 1] = p1 - m - l;
    out[3 * g + 2] = p2 - m - l;
}

// ============ PATH B: fallback (atomic scatter, f32) ============

__global__ void kB_deg(const int* __restrict__ dst, float* __restrict__ deg, int E) {
    int i = blockIdx.x * blockDim.x + threadIdx.x;
    if (i < E) atomicAdd(&deg[dst[i]], 1.0f);
}

__global__ void kB_dinv(float* __restrict__ deg, int n) {
    int i = blockIdx.x * blockDim.x + threadIdx.x;
    if (i < n) deg[i] = rsqrtf(deg[i] + 1.0f);
}

__global__ void kB_agg1(const int* __restrict__ src, const int* __restrict__ dst,
                        const float* __restrict__ dinv, const float* __restrict__ x,
                        float* __restrict__ agg1, int E) {
    int i = blockIdx.x * blockDim.x + threadIdx.x;
    if (i >= E) return;
    int s = src[i], d = dst[i];
    float w = dinv[s] * dinv[d];
    float2 xs = *reinterpret_cast<const float2*>(&x[2 * s]);
    atomicAdd(&agg1[2 * d],     w * xs.x);
    atomicAdd(&agg1[2 * d + 1], w * xs.y);
}

__global__ void kB_z(const float* __restrict__ agg1, const float* __restrict__ x,
                     const float* __restrict__ dinv,
                     const float* __restrict__ W1, const float* __restrict__ b1,
                     const float* __restrict__ W2, float* __restrict__ z, int n) {
    __shared__ float sW1[128], sb1[64], sW2[192];
    for (int t = threadIdx.x; t < 128; t += blockDim.x) sW1[t] = W1[t];
    for (int t = threadIdx.x; t < 64;  t += blockDim.x) sb1[t] = b1[t];
    for (int t = threadIdx.x; t < 192; t += blockDim.x) sW2[t] = W2[t];
    __syncthreads();
    int i = blockIdx.x * blockDim.x + threadIdx.x;
    if (i >= n) return;
    float di = dinv[i], w = di * di;
    float2 xs = *reinterpret_cast<const float2*>(&x[2 * i]);
    float a0 = agg1[2 * i]     + w * xs.x;
    float a1 = agg1[2 * i + 1] + w * xs.y;
    float z0 = 0.f, z1 = 0.f, z2 = 0.f;
#pragma unroll
    for (int j = 0; j < 64; ++j) {
        float h = fmaf(a0, sW1[j], fmaf(a1, sW1[64 + j], sb1[j]));
        h = fmaxf(h, 0.f);
        z0 = fmaf(h, sW2[3 * j],     z0);
        z1 = fmaf(h, sW2[3 * j + 1], z1);
        z2 = fmaf(h, sW2[3 * j + 2], z2);
    }
    z[3 * i] = z0; z[3 * i + 1] = z1; z[3 * i + 2] = z2;
}

__global__ void kB_agg2(const int* __restrict__ src, const int* __restrict__ dst,
                        const float* __restrict__ dinv, const float* __restrict__ z,
                        float* __restrict__ agg2, int E) {
    int i = blockIdx.x * blockDim.x + threadIdx.x;
    if (i >= E) return;
    int s = src[i], d = dst[i];
    float w = dinv[s] * dinv[d];
    atomicAdd(&agg2[3 * d],     w * z[3 * s]);
    atomicAdd(&agg2[3 * d + 1], w * z[3 * s + 1]);
    atomicAdd(&agg2[3 * d + 2], w * z[3 * s + 2]);
}

__global__ void kB_pool(const float* __restrict__ agg2, const float* __restrict__ z,
                        const float* __restrict__ dinv, const float* __restrict__ b2,
                        const int* __restrict__ batch,
                        float* __restrict__ pooled, float* __restrict__ cnt, int n) {
    int i = blockIdx.x * blockDim.x + threadIdx.x;
    if (i >= n) return;
    float di = dinv[i], w = di * di;
    float o0 = agg2[3 * i]     + w * z[3 * i]     + b2[0];
    float o1 = agg2[3 * i + 1] + w * z[3 * i + 1] + b2[1];
    float o2 = agg2[3 * i + 2] + w * z[3 * i + 2] + b2[2];
    int g = batch[i];
    atomicAdd(&pooled[3 * g],     o0);
    atomicAdd(&pooled[3 * g + 1], o1);
    atomicAdd(&pooled[3 * g + 2], o2);
    atomicAdd(&cnt[g], 1.0f);
}

// ============ launch ============

extern "C" void kernel_launch(void* const* d_in, const int* in_sizes, int n_in,
                              void* d_out, int out_size, void* d_ws, size_t ws_size,
                              hipStream_t stream) {
    const float* x     = (const float*)d_in[0];
    const int*   ei    = (const int*)  d_in[1];
    const int*   batch = (const int*)  d_in[2];
    const float* W1    = (const float*)d_in[3];
    const float* b1    = (const float*)d_in[4];
    const float* W2    = (const float*)d_in[5];
    const float* b2    = (const float*)d_in[6];
    float*       out   = (float*)d_out;

    const int n = in_sizes[2];
    const int E = in_sizes[1] / 2;
    const int G = out_size / 3;
    const int* src = ei;
    const int* dst = ei + E;
    const int B = 256;

    const int nbuk  = (n + BUCK - 1) >> SH;
    const int chunk = (((E + NBLK - 1) / NBLK) + 3) & ~3;   // 4-aligned chunks
    const int M     = nbuk * NBLK;
    const int NB2   = (M + SCB - 1) / SCB;

    // Path-A workspace layout (4B units)
    size_t o = 0;
    size_t off_h2   = o; o += M;
    size_t off_rs2  = o; o += M;
    size_t off_bs   = o; o += 1024;
    size_t off_bse  = o; o += 1024;
    size_t off_part = o; o += E;
    size_t off_p2   = o; o += E;
    size_t off_row  = o; o += (size_t)nbuk * BUCK + 1;
    size_t off_dinv = o; o += n;
    size_t off_xw   = o; o += n;              // packed half2
    o = (o + 1) & ~(size_t)1;                 // 8B-align zw
    size_t off_zw   = o; o += (size_t)2 * n;  // packed uint2
    size_t off_pool = o; o += (size_t)3 * G;
    size_t off_cnt  = o; o += G;
    size_t needA = o * 4;

    if (ws_size >= needA && nbuk <= NBUK_MAX && NB2 <= 1024) {
        int*      h2     = (int*)d_ws + off_h2;
        int*      rs2    = (int*)d_ws + off_rs2;
        int*      bs     = (int*)d_ws + off_bs;
        int*      bse    = (int*)d_ws + off_bse;
        int*      part   = (int*)d_ws + off_part;
        int*      part2  = (int*)d_ws + off_p2;
        int*      row    = (int*)d_ws + off_row;
        float*    dinv   = (float*)d_ws + off_dinv;
        unsigned* xw     = (unsigned*)((int*)d_ws + off_xw);
        uint2*    zw     = (uint2*)((int*)d_ws + off_zw);
        float*    pooled = (float*)d_ws + off_pool;
        float*    cnt    = (float*)d_ws + off_cnt;

        hipMemsetAsync(pooled, 0, (size_t)4 * G * 4, stream);  // pooled+cnt contiguous
        k_pcount<<<NBLK, PTH, 0, stream>>>(dst, h2, E, nbuk, chunk);
        k_scanA <<<NB2, SCB, 0, stream>>>(h2, rs2, bs, M);
        k_scanB <<<1, 1024, 0, stream>>>(bs, bse, NB2);
        k_pfill <<<NBLK, PTH, 0, stream>>>(src, dst, rs2, bse, part, E, nbuk, chunk);
        k_prep  <<<nbuk, 512, 0, stream>>>(part, rs2, bse, x, part2, row, dinv, xw, n, nbuk, E);
        k_bz    <<<(4 * n + 255) / 256, 256, 0, stream>>>(part2, row, dinv, xw, W1, b1, W2, zw, n);
        k_bout  <<<(4 * n + 255) / 256, 256, 0, stream>>>(part2, row, dinv, zw, b2, batch, pooled, cnt, n);
        k_out   <<<(G + B - 1) / B, B, 0, stream>>>(pooled, cnt, out, G);
    } else {
        float* ws     = (float*)d_ws;
        float* deg    = ws;
        float* agg1   = deg + n;
        float* agg2   = agg1 + 2 * (size_t)n;
        float* pooled = agg2 + 3 * (size_t)n;
        float* cnt    = pooled + 3 * (size_t)G;
        float* zf     = cnt + G;

        size_t zero_floats = (size_t)6 * n + (size_t)4 * G;
        hipMemsetAsync(ws, 0, zero_floats * sizeof(float), stream);
        kB_deg <<<(E + B - 1) / B, B, 0, stream>>>(dst, deg, E);
        kB_dinv<<<(n + B - 1) / B, B, 0, stream>>>(deg, n);
        kB_agg1<<<(E + B - 1) / B, B, 0, stream>>>(src, dst, deg, x, agg1, E);
        kB_z   <<<(n + B - 1) / B, B, 0, stream>>>(agg1, x, deg, W1, b1, W2, zf, n);
        kB_agg2<<<(E + B - 1) / B, B, 0, stream>>>(src, dst, deg, zf, agg2, E);
        kB_pool<<<(n + B - 1) / B, B, 0, stream>>>(agg2, zf, deg, b2, batch, pooled, cnt, n);
        k_out  <<<(G + B - 1) / B, B, 0, stream>>>(pooled, cnt, out, G);
    }
}

// Round 10
// 127.068 us; speedup vs baseline: 1.3752x; 1.0413x over previous
//
#include <hip/hip_runtime.h>
#include <hip/hip_fp16.h>

#define NBLK 1024         // partition blocks
#define PTH  512          // pcount/pfill threads
#define SH   9
#define BUCK 512          // nodes per bucket = 1<<SH
#define NBUK_MAX 512
#define SCB  512          // scanA block width
#define PREP_CAP 10240    // max staged edges per bucket in k_prep (40KB LDS)
#define TILE 4096         // pfill per-tile staged edges

__device__ __forceinline__ unsigned pack2(float a, float b) {
    __half ha = __float2half_rn(a), hb = __float2half_rn(b);
    unsigned short ua = *reinterpret_cast<unsigned short*>(&ha);
    unsigned short ub = *reinterpret_cast<unsigned short*>(&hb);
    return ((unsigned)ub << 16) | ua;
}
__device__ __forceinline__ float2 unpack2(unsigned u) {
    unsigned short ua = (unsigned short)(u & 0xffff), ub = (unsigned short)(u >> 16);
    __half ha = *reinterpret_cast<__half*>(&ua), hb = *reinterpret_cast<__half*>(&ub);
    return make_float2(__half2float(ha), __half2float(hb));
}

// ============ PATH A: bucket sort -> exact CSR -> 4-lane gathers (f16 payloads) ============

// Pass A: per-block LDS histogram of dst buckets (int4-vectorized)
__global__ void __launch_bounds__(PTH) k_pcount(const int* __restrict__ dst,
                                                int* __restrict__ hist2d,
                                                int E, int nbuk, int chunk) {
    __shared__ int h[NBUK_MAX];
    for (int t = threadIdx.x; t < nbuk; t += PTH) h[t] = 0;
    __syncthreads();
    int beg = blockIdx.x * chunk, end = min(beg + chunk, E);   // beg 4-aligned (chunk%4==0)
    int len = end - beg;
    if (len > 0) {
        int nq = len >> 2;
        for (int q = threadIdx.x; q < nq; q += PTH) {
            int4 d4 = *reinterpret_cast<const int4*>(&dst[beg + (q << 2)]);
            atomicAdd(&h[d4.x >> SH], 1);
            atomicAdd(&h[d4.y >> SH], 1);
            atomicAdd(&h[d4.z >> SH], 1);
            atomicAdd(&h[d4.w >> SH], 1);
        }
        for (int i = beg + (nq << 2) + threadIdx.x; i < end; i += PTH)
            atomicAdd(&h[dst[i] >> SH], 1);
    }
    __syncthreads();
    for (int t = threadIdx.x; t < nbuk; t += PTH)
        hist2d[t * NBLK + blockIdx.x] = h[t];
}

__global__ void __launch_bounds__(SCB) k_scanA(const int* __restrict__ in,
                                               int* __restrict__ outp,
                                               int* __restrict__ bsum, int M) {
    __shared__ int s[SCB];
    int t = threadIdx.x, i = blockIdx.x * SCB + t;
    int h = (i < M) ? in[i] : 0;
    s[t] = h; __syncthreads();
    for (int off = 1; off < SCB; off <<= 1) {
        int v = (t >= off) ? s[t - off] : 0;
        __syncthreads();
        s[t] += v;
        __syncthreads();
    }
    if (i < M) outp[i] = s[t] - h;
    if (t == SCB - 1) bsum[blockIdx.x] = s[SCB - 1];
}

__global__ void k_scanB(const int* __restrict__ bsum, int* __restrict__ bsum_ex, int NB) {
    __shared__ int s[1024];
    int t = threadIdx.x;
    int v = (t < NB) ? bsum[t] : 0;
    s[t] = v; __syncthreads();
    for (int off = 1; off < 1024; off <<= 1) {
        int u = (t >= off) ? s[t - off] : 0;
        __syncthreads();
        s[t] += u;
        __syncthreads();
    }
    if (t < NB) bsum_ex[t] = s[t] - v;
}

__device__ __forceinline__ int scan_off(const int* rs2, const int* bse, int j) {
    return rs2[j] + bse[j >> 9];          // SCB=512
}

// Pass B: chunk-local LDS counting sort -> COALESCED writes of bucket runs.
// Direct per-position bucket-id lookup (lbk) replaces binary search.
__global__ void __launch_bounds__(PTH) k_pfill(const int* __restrict__ src,
                                               const int* __restrict__ dst,
                                               const int* __restrict__ rs2,
                                               const int* __restrict__ bse,
                                               int* __restrict__ part,
                                               int E, int nbuk, int chunk) {
    __shared__ int gcur[NBUK_MAX];     // block's global cursor per bucket
    __shared__ int hist[NBUK_MAX];
    __shared__ int scn[NBUK_MAX];      // inclusive scan of hist
    __shared__ int lcur[NBUK_MAX];     // tile-local cursors
    __shared__ int lout[TILE];         // tile-local bucket-sorted packed edges
    __shared__ unsigned short lbk[TILE];  // bucket id per local position
    int t = threadIdx.x, b = blockIdx.x;
    for (int u = t; u < nbuk; u += PTH)
        gcur[u] = scan_off(rs2, bse, u * NBLK + b);
    int beg = b * chunk, end = min(beg + chunk, E);
    for (int tb = beg; tb < end; tb += TILE) {      // tb stays 4-aligned
        int te = min(tb + TILE, end), cnt = te - tb;
        int nq = cnt >> 2;
        for (int u = t; u < nbuk; u += PTH) hist[u] = 0;
        __syncthreads();
        for (int q = t; q < nq; q += PTH) {
            int4 d4 = *reinterpret_cast<const int4*>(&dst[tb + (q << 2)]);
            atomicAdd(&hist[d4.x >> SH], 1);
            atomicAdd(&hist[d4.y >> SH], 1);
            atomicAdd(&hist[d4.z >> SH], 1);
            atomicAdd(&hist[d4.w >> SH], 1);
        }
        for (int i = tb + (nq << 2) + t; i < te; i += PTH)
            atomicAdd(&hist[dst[i] >> SH], 1);
        __syncthreads();
        int v = (t < nbuk) ? hist[t] : 0;
        scn[t] = v; __syncthreads();
        for (int off = 1; off < PTH; off <<= 1) {
            int u = (t >= off) ? scn[t - off] : 0;
            __syncthreads();
            scn[t] += u;
            __syncthreads();
        }
        if (t < nbuk) lcur[t] = scn[t] - hist[t];  // exclusive
        __syncthreads();
        for (int q = t; q < nq; q += PTH) {        // placement (int4 reads)
            int base = tb + (q << 2);
            int4 d4 = *reinterpret_cast<const int4*>(&dst[base]);
            int4 s4 = *reinterpret_cast<const int4*>(&src[base]);
            int bk, p;
            bk = d4.x >> SH; p = atomicAdd(&lcur[bk], 1);
            lout[p] = (s4.x << SH) | (d4.x & (BUCK - 1)); lbk[p] = (unsigned short)bk;
            bk = d4.y >> SH; p = atomicAdd(&lcur[bk], 1);
            lout[p] = (s4.y << SH) | (d4.y & (BUCK - 1)); lbk[p] = (unsigned short)bk;
            bk = d4.z >> SH; p = atomicAdd(&lcur[bk], 1);
            lout[p] = (s4.z << SH) | (d4.z & (BUCK - 1)); lbk[p] = (unsigned short)bk;
            bk = d4.w >> SH; p = atomicAdd(&lcur[bk], 1);
            lout[p] = (s4.w << SH) | (d4.w & (BUCK - 1)); lbk[p] = (unsigned short)bk;
        }
        for (int i = tb + (nq << 2) + t; i < te; i += PTH) {
            int d = dst[i];
            int bk = d >> SH;
            int p = atomicAdd(&lcur[bk], 1);
            lout[p] = (src[i] << SH) | (d & (BUCK - 1)); lbk[p] = (unsigned short)bk;
        }
        __syncthreads();
        // coalesced copy-out with direct lookup
        for (int j = t; j < cnt; j += PTH) {
            int bk = lbk[j];
            part[gcur[bk] + (j - (scn[bk] - hist[bk]))] = lout[j];
        }
        __syncthreads();
        for (int u = t; u < nbuk; u += PTH) gcur[u] += hist[u];
        __syncthreads();
    }
}

// per bucket: hist -> scan -> LDS-staged scatter into dst-sorted part2;
// rowstart, dinv, xw = half2(dinv*x)
__global__ void __launch_bounds__(512) k_prep(
        const int* __restrict__ part, const int* __restrict__ rs2,
        const int* __restrict__ bse, const float* __restrict__ x,
        int* __restrict__ part2, int* __restrict__ rowstart,
        float* __restrict__ dinv, unsigned* __restrict__ xw,
        int n, int nbuk, int E) {
    __shared__ int hist[BUCK];
    __shared__ int s[BUCK];
    __shared__ int cur[BUCK];
    __shared__ int outbuf[PREP_CAP];
    int t = threadIdx.x, b = blockIdx.x;
    hist[t] = 0;
    __syncthreads();
    int beg = scan_off(rs2, bse, b * NBLK);
    int end = (b + 1 < nbuk) ? scan_off(rs2, bse, (b + 1) * NBLK) : E;
    int ab = (beg + 3) & ~3; if (ab > end) ab = end;
    int tstart = ab + ((end - ab) & ~3);
    for (int i = beg + t; i < ab; i += 512)
        atomicAdd(&hist[part[i] & (BUCK - 1)], 1);
    for (int i = ab + t * 4; i + 3 < end; i += 512 * 4) {
        int4 e4 = *reinterpret_cast<const int4*>(&part[i]);
        atomicAdd(&hist[e4.x & (BUCK - 1)], 1);
        atomicAdd(&hist[e4.y & (BUCK - 1)], 1);
        atomicAdd(&hist[e4.z & (BUCK - 1)], 1);
        atomicAdd(&hist[e4.w & (BUCK - 1)], 1);
    }
    for (int i = tstart + t; i < end; i += 512)
        atomicAdd(&hist[part[i] & (BUCK - 1)], 1);
    __syncthreads();
    s[t] = hist[t];
    __syncthreads();
    for (int d = 1; d < 512; d <<= 1) {
        int v = (t >= d) ? s[t - d] : 0;
        __syncthreads();
        s[t] += v;
        __syncthreads();
    }
    int excl = s[t] - hist[t];
    cur[t] = excl;                       // bucket-local cursor
    int node = (b << SH) + t;
    rowstart[node] = beg + excl;
    if (node < n) {
        float di = rsqrtf((float)hist[t] + 1.0f);
        dinv[node] = di;
        float2 xs = *reinterpret_cast<const float2*>(&x[2 * node]);
        xw[node] = pack2(di * xs.x, di * xs.y);
    }
    __syncthreads();
    int cnt = end - beg;
    bool staged = (cnt <= PREP_CAP);
    if (staged) {
        for (int i = beg + t; i < ab; i += 512) {
            int e = part[i];
            int p = atomicAdd(&cur[e & (BUCK - 1)], 1);
            outbuf[p] = e >> SH;
        }
        for (int i = ab + t * 4; i + 3 < end; i += 512 * 4) {
            int4 e4 = *reinterpret_cast<const int4*>(&part[i]);
            int p;
            p = atomicAdd(&cur[e4.x & (BUCK - 1)], 1); outbuf[p] = e4.x >> SH;
            p = atomicAdd(&cur[e4.y & (BUCK - 1)], 1); outbuf[p] = e4.y >> SH;
            p = atomicAdd(&cur[e4.z & (BUCK - 1)], 1); outbuf[p] = e4.z >> SH;
            p = atomicAdd(&cur[e4.w & (BUCK - 1)], 1); outbuf[p] = e4.w >> SH;
        }
        for (int i = tstart + t; i < end; i += 512) {
            int e = part[i];
            int p = atomicAdd(&cur[e & (BUCK - 1)], 1);
            outbuf[p] = e >> SH;
        }
        __syncthreads();
        for (int i = t; i < cnt; i += 512)
            part2[beg + i] = outbuf[i];             // coalesced
    } else {
        for (int i = beg + t; i < end; i += 512) {
            int e = part[i];
            int p = atomicAdd(&cur[e & (BUCK - 1)], 1);
            part2[beg + p] = e >> SH;
        }
    }
}

// layer-1: 4 lanes/node, unrolled 4B half2 gathers + butterfly; MLP 16 hidden/lane
__global__ void __launch_bounds__(256) k_bz(
        const int* __restrict__ part2, const int* __restrict__ rowstart,
        const float* __restrict__ dinv, const unsigned* __restrict__ xw,
        const float* __restrict__ W1, const float* __restrict__ b1,
        const float* __restrict__ W2, uint2* __restrict__ zw, int n) {
    __shared__ float sW1[128], sb1[64], sW2[192];
    for (int t = threadIdx.x; t < 128; t += 256) sW1[t] = W1[t];
    for (int t = threadIdx.x; t < 64;  t += 256) sb1[t] = b1[t];
    for (int t = threadIdx.x; t < 192; t += 256) sW2[t] = W2[t];
    __syncthreads();
    int tid = blockIdx.x * 256 + threadIdx.x;
    int i = tid >> 2, lane = tid & 3;
    if (i >= n) return;
    int beg = rowstart[i], end = rowstart[i + 1];
    float a0 = 0.f, a1 = 0.f;
    int e = beg + lane;
    for (; e + 4 < end; e += 8) {
        int s0 = part2[e];
        int s1 = part2[e + 4];
        float2 v0 = unpack2(xw[s0]);
        float2 v1 = unpack2(xw[s1]);
        a0 += v0.x + v1.x;
        a1 += v0.y + v1.y;
    }
    if (e < end) {
        float2 v = unpack2(xw[part2[e]]);
        a0 += v.x; a1 += v.y;
    }
    if (lane == 0) {
        float2 self = unpack2(xw[i]);
        a0 += self.x; a1 += self.y;
    }
    a0 += __shfl_xor(a0, 1); a0 += __shfl_xor(a0, 2);
    a1 += __shfl_xor(a1, 1); a1 += __shfl_xor(a1, 2);
    float di = dinv[i];
    a0 *= di; a1 *= di;
    float z0 = 0.f, z1 = 0.f, z2 = 0.f;
    int j0 = lane << 4;
#pragma unroll
    for (int jj = 0; jj < 16; ++jj) {
        int j = j0 + jj;
        float h = fmaf(a0, sW1[j], fmaf(a1, sW1[64 + j], sb1[j]));
        h = fmaxf(h, 0.f);
        z0 = fmaf(h, sW2[3 * j],     z0);
        z1 = fmaf(h, sW2[3 * j + 1], z1);
        z2 = fmaf(h, sW2[3 * j + 2], z2);
    }
    z0 += __shfl_xor(z0, 1); z0 += __shfl_xor(z0, 2);
    z1 += __shfl_xor(z1, 1); z1 += __shfl_xor(z1, 2);
    z2 += __shfl_xor(z2, 1); z2 += __shfl_xor(z2, 2);
    if (lane == 0)
        zw[i] = make_uint2(pack2(di * z0, di * z1), pack2(di * z2, 0.f));
}

// layer-2: 4 lanes/node, unrolled 8B gathers + butterfly; epilogue + wave pooling
__global__ void __launch_bounds__(256) k_bout(
        const int* __restrict__ part2, const int* __restrict__ rowstart,
        const float* __restrict__ dinv, const uint2* __restrict__ zw,
        const float* __restrict__ b2, const int* __restrict__ batch,
        float* __restrict__ pooled, float* __restrict__ cnt, int n) {
    int tid = blockIdx.x * 256 + threadIdx.x;
    int i = tid >> 2, lane = tid & 3;
    float o0 = 0.f, o1 = 0.f, o2 = 0.f, vc = 0.f;
    int g = -1;
    if (i < n) {
        int beg = rowstart[i], end = rowstart[i + 1];
        float a0 = 0.f, a1 = 0.f, a2 = 0.f;
        int e = beg + lane;
        for (; e + 4 < end; e += 8) {
            int s0 = part2[e];
            int s1 = part2[e + 4];
            uint2 u0 = zw[s0];
            uint2 u1 = zw[s1];
            float2 p0 = unpack2(u0.x), p1 = unpack2(u1.x);
            a0 += p0.x + p1.x;
            a1 += p0.y + p1.y;
            a2 += unpack2(u0.y).x + unpack2(u1.y).x;
        }
        if (e < end) {
            uint2 u = zw[part2[e]];
            float2 p = unpack2(u.x);
            a0 += p.x; a1 += p.y; a2 += unpack2(u.y).x;
        }
        if (lane == 0) {
            uint2 u = zw[i];
            float2 p = unpack2(u.x);
            a0 += p.x; a1 += p.y; a2 += unpack2(u.y).x;
        }
        a0 += __shfl_xor(a0, 1); a0 += __shfl_xor(a0, 2);
        a1 += __shfl_xor(a1, 1); a1 += __shfl_xor(a1, 2);
        a2 += __shfl_xor(a2, 1); a2 += __shfl_xor(a2, 2);
        if (lane == 0) {
            float di = dinv[i];
            o0 = fmaf(di, a0, b2[0]);
            o1 = fmaf(di, a1, b2[1]);
            o2 = fmaf(di, a2, b2[2]);
            vc = 1.f;
        }
        g = batch[i];
    }
    int g0 = __shfl(g, 0);
    bool uni = __all(g == g0);
    if (uni) {
        for (int off = 32; off; off >>= 1) {
            o0 += __shfl_down(o0, off);
            o1 += __shfl_down(o1, off);
            o2 += __shfl_down(o2, off);
            vc += __shfl_down(vc, off);
        }
        if ((threadIdx.x & 63) == 0 && g0 >= 0) {
            atomicAdd(&pooled[3 * g0],     o0);
            atomicAdd(&pooled[3 * g0 + 1], o1);
            atomicAdd(&pooled[3 * g0 + 2], o2);
            atomicAdd(&cnt[g0], vc);
        }
    } else if (g >= 0 && lane == 0) {
        atomicAdd(&pooled[3 * g],     o0);
        atomicAdd(&pooled[3 * g + 1], o1);
        atomicAdd(&pooled[3 * g + 2], o2);
        atomicAdd(&cnt[g], 1.f);
    }
}

__global__ void k_out(const float* __restrict__ pooled, const float* __restrict__ cnt,
                      float* __restrict__ out, int G) {
    int g = blockIdx.x * blockDim.x + threadIdx.x;
    if (g >= G) return;
    float c = fmaxf(cnt[g], 1.0f);
    float p0 = pooled[3 * g] / c, p1 = pooled[3 * g + 1] / c, p2 = pooled[3 * g + 2] / c;
    float m = fmaxf(p0, fmaxf(p1, p2));
    float s = expf(p0 - m) + expf(p1 - m) + expf(p2 - m);
    float l = logf(s);
    out[3 * g]     = p0 - m - l;
    out[3 * g + 1] = p1 - m - l;
    out[3 * g + 2] = p2 - m - l;
}

// ============ PATH B: fallback (atomic scatter, f32) ============

__global__ void kB_deg(const int* __restrict__ dst, float* __restrict__ deg, int E) {
    int i = blockIdx.x * blockDim.x + threadIdx.x;
    if (i < E) atomicAdd(&deg[dst[i]], 1.0f);
}

__global__ void kB_dinv(float* __restrict__ deg, int n) {
    int i = blockIdx.x * blockDim.x + threadIdx.x;
    if (i < n) deg[i] = rsqrtf(deg[i] + 1.0f);
}

__global__ void kB_agg1(const int* __restrict__ src, const int* __restrict__ dst,
                        const float* __restrict__ dinv, const float* __restrict__ x,
                        float* __restrict__ agg1, int E) {
    int i = blockIdx.x * blockDim.x + threadIdx.x;
    if (i >= E) return;
    int s = src[i], d = dst[i];
    float w = dinv[s] * dinv[d];
    float2 xs = *reinterpret_cast<const float2*>(&x[2 * s]);
    atomicAdd(&agg1[2 * d],     w * xs.x);
    atomicAdd(&agg1[2 * d + 1], w * xs.y);
}

__global__ void kB_z(const float* __restrict__ agg1, const float* __restrict__ x,
                     const float* __restrict__ dinv,
                     const float* __restrict__ W1, const float* __restrict__ b1,
                     const float* __restrict__ W2, float* __restrict__ z, int n) {
    __shared__ float sW1[128], sb1[64], sW2[192];
    for (int t = threadIdx.x; t < 128; t += blockDim.x) sW1[t] = W1[t];
    for (int t = threadIdx.x; t < 64;  t += blockDim.x) sb1[t] = b1[t];
    for (int t = threadIdx.x; t < 192; t += blockDim.x) sW2[t] = W2[t];
    __syncthreads();
    int i = blockIdx.x * blockDim.x + threadIdx.x;
    if (i >= n) return;
    float di = dinv[i], w = di * di;
    float2 xs = *reinterpret_cast<const float2*>(&x[2 * i]);
    float a0 = agg1[2 * i]     + w * xs.x;
    float a1 = agg1[2 * i + 1] + w * xs.y;
    float z0 = 0.f, z1 = 0.f, z2 = 0.f;
#pragma unroll
    for (int j = 0; j < 64; ++j) {
        float h = fmaf(a0, sW1[j], fmaf(a1, sW1[64 + j], sb1[j]));
        h = fmaxf(h, 0.f);
        z0 = fmaf(h, sW2[3 * j],     z0);
        z1 = fmaf(h, sW2[3 * j + 1], z1);
        z2 = fmaf(h, sW2[3 * j + 2], z2);
    }
    z[3 * i] = z0; z[3 * i + 1] = z1; z[3 * i + 2] = z2;
}

__global__ void kB_agg2(const int* __restrict__ src, const int* __restrict__ dst,
                        const float* __restrict__ dinv, const float* __restrict__ z,
                        float* __restrict__ agg2, int E) {
    int i = blockIdx.x * blockDim.x + threadIdx.x;
    if (i >= E) return;
    int s = src[i], d = dst[i];
    float w = dinv[s] * dinv[d];
    atomicAdd(&agg2[3 * d],     w * z[3 * s]);
    atomicAdd(&agg2[3 * d + 1], w * z[3 * s + 1]);
    atomicAdd(&agg2[3 * d + 2], w * z[3 * s + 2]);
}

__global__ void kB_pool(const float* __restrict__ agg2, const float* __restrict__ z,
                        const float* __restrict__ dinv, const float* __restrict__ b2,
                        const int* __restrict__ batch,
                        float* __restrict__ pooled, float* __restrict__ cnt, int n) {
    int i = blockIdx.x * blockDim.x + threadIdx.x;
    if (i >= n) return;
    float di = dinv[i], w = di * di;
    float o0 = agg2[3 * i]     + w * z[3 * i]     + b2[0];
    float o1 = agg2[3 * i + 1] + w * z[3 * i + 1] + b2[1];
    float o2 = agg2[3 * i + 2] + w * z[3 * i + 2] + b2[2];
    int g = batch[i];
    atomicAdd(&pooled[3 * g],     o0);
    atomicAdd(&pooled[3 * g + 1], o1);
    atomicAdd(&pooled[3 * g + 2], o2);
    atomicAdd(&cnt[g], 1.0f);
}

// ============ launch ============

extern "C" void kernel_launch(void* const* d_in, const int* in_sizes, int n_in,
                              void* d_out, int out_size, void* d_ws, size_t ws_size,
                              hipStream_t stream) {
    const float* x     = (const float*)d_in[0];
    const int*   ei    = (const int*)  d_in[1];
    const int*   batch = (const int*)  d_in[2];
    const float* W1    = (const float*)d_in[3];
    const float* b1    = (const float*)d_in[4];
    const float* W2    = (const float*)d_in[5];
    const float* b2    = (const float*)d_in[6];
    float*       out   = (float*)d_out;

    const int n = in_sizes[2];
    const int E = in_sizes[1] / 2;
    const int G = out_size / 3;
    const int* src = ei;
    const int* dst = ei + E;
    const int B = 256;

    const int nbuk  = (n + BUCK - 1) >> SH;
    const int chunk = (((E + NBLK - 1) / NBLK) + 3) & ~3;   // 4-aligned chunks
    const int M     = nbuk * NBLK;
    const int NB2   = (M + SCB - 1) / SCB;

    // Path-A workspace layout (4B units)
    size_t o = 0;
    size_t off_h2   = o; o += M;
    size_t off_rs2  = o; o += M;
    size_t off_bs   = o; o += 1024;
    size_t off_bse  = o; o += 1024;
    size_t off_part = o; o += E;
    size_t off_p2   = o; o += E;
    size_t off_row  = o; o += (size_t)nbuk * BUCK + 1;
    size_t off_dinv = o; o += n;
    size_t off_xw   = o; o += n;              // packed half2
    o = (o + 1) & ~(size_t)1;                 // 8B-align zw
    size_t off_zw   = o; o += (size_t)2 * n;  // packed uint2
    size_t off_pool = o; o += (size_t)3 * G;
    size_t off_cnt  = o; o += G;
    size_t needA = o * 4;

    if (ws_size >= needA && nbuk <= NBUK_MAX && NB2 <= 1024) {
        int*      h2     = (int*)d_ws + off_h2;
        int*      rs2    = (int*)d_ws + off_rs2;
        int*      bs     = (int*)d_ws + off_bs;
        int*      bse    = (int*)d_ws + off_bse;
        int*      part   = (int*)d_ws + off_part;
        int*      part2  = (int*)d_ws + off_p2;
        int*      row    = (int*)d_ws + off_row;
        float*    dinv   = (float*)d_ws + off_dinv;
        unsigned* xw     = (unsigned*)((int*)d_ws + off_xw);
        uint2*    zw     = (uint2*)((int*)d_ws + off_zw);
        float*    pooled = (float*)d_ws + off_pool;
        float*    cnt    = (float*)d_ws + off_cnt;

        hipMemsetAsync(pooled, 0, (size_t)4 * G * 4, stream);  // pooled+cnt contiguous
        k_pcount<<<NBLK, PTH, 0, stream>>>(dst, h2, E, nbuk, chunk);
        k_scanA <<<NB2, SCB, 0, stream>>>(h2, rs2, bs, M);
        k_scanB <<<1, 1024, 0, stream>>>(bs, bse, NB2);
        k_pfill <<<NBLK, PTH, 0, stream>>>(src, dst, rs2, bse, part, E, nbuk, chunk);
        k_prep  <<<nbuk, 512, 0, stream>>>(part, rs2, bse, x, part2, row, dinv, xw, n, nbuk, E);
        k_bz    <<<(4 * n + 255) / 256, 256, 0, stream>>>(part2, row, dinv, xw, W1, b1, W2, zw, n);
        k_bout  <<<(4 * n + 255) / 256, 256, 0, stream>>>(part2, row, dinv, zw, b2, batch, pooled, cnt, n);
        k_out   <<<(G + B - 1) / B, B, 0, stream>>>(pooled, cnt, out, G);
    } else {
        float* ws     = (float*)d_ws;
        float* deg    = ws;
        float* agg1   = deg + n;
        float* agg2   = agg1 + 2 * (size_t)n;
        float* pooled = agg2 + 3 * (size_t)n;
        float* cnt    = pooled + 3 * (size_t)G;
        float* zf     = cnt + G;

        size_t zero_floats = (size_t)6 * n + (size_t)4 * G;
        hipMemsetAsync(ws, 0, zero_floats * sizeof(float), stream);
        kB_deg <<<(E + B - 1) / B, B, 0, stream>>>(dst, deg, E);
        kB_dinv<<<(n + B - 1) / B, B, 0, stream>>>(deg, n);
        kB_agg1<<<(E + B - 1) / B, B, 0, stream>>>(src, dst, deg, x, agg1, E);
        kB_z   <<<(n + B - 1) / B, B, 0, stream>>>(agg1, x, deg, W1, b1, W2, zf, n);
        kB_agg2<<<(E + B - 1) / B, B, 0, stream>>>(src, dst, deg, zf, agg2, E);
        kB_pool<<<(n + B - 1) / B, B, 0, stream>>>(agg2, zf, deg, b2, batch, pooled, cnt, n);
        k_out  <<<(G + B - 1) / B, B, 0, stream>>>(pooled, cnt, out, G);
    }
}

// Round 11
// 124.518 us; speedup vs baseline: 1.4034x; 1.0205x over previous
//
#include <hip/hip_runtime.h>
#include <hip/hip_fp16.h>
#include <math.h>

#define NBLK 1024         // partition blocks
#define PTH  512          // pfill threads
#define SH   9
#define BUCK 512          // nodes per bucket = 1<<SH
#define NBUK_MAX 512
#define CAP  10240        // fixed per-bucket region capacity (multiple of 4)
#define TILE 4096         // pfill per-tile staged edges

__device__ __forceinline__ unsigned pack2(float a, float b) {
    __half ha = __float2half_rn(a), hb = __float2half_rn(b);
    unsigned short ua = *reinterpret_cast<unsigned short*>(&ha);
    unsigned short ub = *reinterpret_cast<unsigned short*>(&hb);
    return ((unsigned)ub << 16) | ua;
}
__device__ __forceinline__ float2 unpack2(unsigned u) {
    unsigned short ua = (unsigned short)(u & 0xffff), ub = (unsigned short)(u >> 16);
    __half ha = *reinterpret_cast<__half*>(&ua), hb = *reinterpret_cast<__half*>(&ub);
    return make_float2(__half2float(ha), __half2float(hb));
}

// ============ PATH A: single-pass bucket sort (atomic reservation) -> CSR -> gathers ============

// tile-local LDS counting sort; per-tile global reservation via bcnt; coalesced copy-out
__global__ void __launch_bounds__(PTH) k_pfill(const int* __restrict__ src,
                                               const int* __restrict__ dst,
                                               int* __restrict__ bcnt,
                                               int* __restrict__ part,
                                               int E, int nbuk, int chunk) {
    __shared__ int hist[NBUK_MAX];
    __shared__ int scn[NBUK_MAX];      // inclusive scan of hist
    __shared__ int lcur[NBUK_MAX];     // tile-local cursors
    __shared__ int resv[NBUK_MAX];     // per-tile global reservation base
    __shared__ int lout[TILE];
    __shared__ unsigned short lbk[TILE];
    int t = threadIdx.x, b = blockIdx.x;
    int beg = b * chunk, end = min(beg + chunk, E);
    for (int tb = beg; tb < end; tb += TILE) {      // tb stays 4-aligned
        int te = min(tb + TILE, end), cnt = te - tb;
        int nq = cnt >> 2;
        for (int u = t; u < nbuk; u += PTH) hist[u] = 0;
        __syncthreads();
        for (int q = t; q < nq; q += PTH) {
            int4 d4 = *reinterpret_cast<const int4*>(&dst[tb + (q << 2)]);
            atomicAdd(&hist[d4.x >> SH], 1);
            atomicAdd(&hist[d4.y >> SH], 1);
            atomicAdd(&hist[d4.z >> SH], 1);
            atomicAdd(&hist[d4.w >> SH], 1);
        }
        for (int i = tb + (nq << 2) + t; i < te; i += PTH)
            atomicAdd(&hist[dst[i] >> SH], 1);
        __syncthreads();
        int v = (t < nbuk) ? hist[t] : 0;
        scn[t] = v; __syncthreads();
        for (int off = 1; off < PTH; off <<= 1) {
            int u = (t >= off) ? scn[t - off] : 0;
            __syncthreads();
            scn[t] += u;
            __syncthreads();
        }
        if (t < nbuk) {
            lcur[t] = scn[t] - hist[t];            // exclusive
            resv[t] = (hist[t] > 0) ? atomicAdd(&bcnt[t], hist[t]) : 0;
        }
        __syncthreads();
        for (int q = t; q < nq; q += PTH) {        // placement (int4 reads)
            int base = tb + (q << 2);
            int4 d4 = *reinterpret_cast<const int4*>(&dst[base]);
            int4 s4 = *reinterpret_cast<const int4*>(&src[base]);
            int bk, p;
            bk = d4.x >> SH; p = atomicAdd(&lcur[bk], 1);
            lout[p] = (s4.x << SH) | (d4.x & (BUCK - 1)); lbk[p] = (unsigned short)bk;
            bk = d4.y >> SH; p = atomicAdd(&lcur[bk], 1);
            lout[p] = (s4.y << SH) | (d4.y & (BUCK - 1)); lbk[p] = (unsigned short)bk;
            bk = d4.z >> SH; p = atomicAdd(&lcur[bk], 1);
            lout[p] = (s4.z << SH) | (d4.z & (BUCK - 1)); lbk[p] = (unsigned short)bk;
            bk = d4.w >> SH; p = atomicAdd(&lcur[bk], 1);
            lout[p] = (s4.w << SH) | (d4.w & (BUCK - 1)); lbk[p] = (unsigned short)bk;
        }
        for (int i = tb + (nq << 2) + t; i < te; i += PTH) {
            int d = dst[i];
            int bk = d >> SH;
            int p = atomicAdd(&lcur[bk], 1);
            lout[p] = (src[i] << SH) | (d & (BUCK - 1)); lbk[p] = (unsigned short)bk;
        }
        __syncthreads();
        // coalesced copy-out into fixed-cap bucket region
        for (int j = t; j < cnt; j += PTH) {
            int bk = lbk[j];
            part[bk * CAP + resv[bk] + (j - (scn[bk] - hist[bk]))] = lout[j];
        }
        __syncthreads();
    }
}

// per bucket: hist -> scan -> LDS-staged scatter into dst-sorted part2 (same region);
// rowstart (absolute), rowlen, dinv, xw = half2(dinv*x)
__global__ void __launch_bounds__(512) k_prep(
        const int* __restrict__ part, const int* __restrict__ bcnt,
        const float* __restrict__ x,
        int* __restrict__ part2, int* __restrict__ rowstart, int* __restrict__ rowlen,
        float* __restrict__ dinv, unsigned* __restrict__ xw, int n) {
    __shared__ int hist[BUCK];
    __shared__ int s[BUCK];
    __shared__ int cur[BUCK];
    __shared__ int outbuf[CAP];
    int t = threadIdx.x, b = blockIdx.x;
    hist[t] = 0;
    __syncthreads();
    int beg = b * CAP;                 // 4-aligned
    int cnt = bcnt[b];
    int end = beg + cnt;
    int nq = cnt >> 2;
    for (int q = t; q < nq; q += 512) {
        int4 e4 = *reinterpret_cast<const int4*>(&part[beg + (q << 2)]);
        atomicAdd(&hist[e4.x & (BUCK - 1)], 1);
        atomicAdd(&hist[e4.y & (BUCK - 1)], 1);
        atomicAdd(&hist[e4.z & (BUCK - 1)], 1);
        atomicAdd(&hist[e4.w & (BUCK - 1)], 1);
    }
    for (int i = beg + (nq << 2) + t; i < end; i += 512)
        atomicAdd(&hist[part[i] & (BUCK - 1)], 1);
    __syncthreads();
    s[t] = hist[t];
    __syncthreads();
    for (int d = 1; d < 512; d <<= 1) {
        int v = (t >= d) ? s[t - d] : 0;
        __syncthreads();
        s[t] += v;
        __syncthreads();
    }
    int excl = s[t] - hist[t];
    cur[t] = excl;                     // bucket-local cursor
    int node = (b << SH) + t;
    if (node < n) {
        rowstart[node] = beg + excl;
        rowlen[node]   = hist[t];
        float di = rsqrtf((float)hist[t] + 1.0f);
        dinv[node] = di;
        float2 xs = *reinterpret_cast<const float2*>(&x[2 * node]);
        xw[node] = pack2(di * xs.x, di * xs.y);
    }
    __syncthreads();
    for (int q = t; q < nq; q += 512) {            // staged scatter (int4 reads)
        int4 e4 = *reinterpret_cast<const int4*>(&part[beg + (q << 2)]);
        int p;
        p = atomicAdd(&cur[e4.x & (BUCK - 1)], 1); outbuf[p] = e4.x >> SH;
        p = atomicAdd(&cur[e4.y & (BUCK - 1)], 1); outbuf[p] = e4.y >> SH;
        p = atomicAdd(&cur[e4.z & (BUCK - 1)], 1); outbuf[p] = e4.z >> SH;
        p = atomicAdd(&cur[e4.w & (BUCK - 1)], 1); outbuf[p] = e4.w >> SH;
    }
    for (int i = beg + (nq << 2) + t; i < end; i += 512) {
        int e = part[i];
        int p = atomicAdd(&cur[e & (BUCK - 1)], 1);
        outbuf[p] = e >> SH;
    }
    __syncthreads();
    for (int i = t; i < cnt; i += 512)
        part2[beg + i] = outbuf[i];                 // coalesced
}

// layer-1: 4 lanes/node, unrolled 4B half2 gathers + butterfly; MLP 16 hidden/lane
__global__ void __launch_bounds__(256) k_bz(
        const int* __restrict__ part2, const int* __restrict__ rowstart,
        const int* __restrict__ rowlen,
        const float* __restrict__ dinv, const unsigned* __restrict__ xw,
        const float* __restrict__ W1, const float* __restrict__ b1,
        const float* __restrict__ W2, uint2* __restrict__ zw, int n) {
    __shared__ float sW1[128], sb1[64], sW2[192];
    for (int t = threadIdx.x; t < 128; t += 256) sW1[t] = W1[t];
    for (int t = threadIdx.x; t < 64;  t += 256) sb1[t] = b1[t];
    for (int t = threadIdx.x; t < 192; t += 256) sW2[t] = W2[t];
    __syncthreads();
    int tid = blockIdx.x * 256 + threadIdx.x;
    int i = tid >> 2, lane = tid & 3;
    if (i >= n) return;
    int beg = rowstart[i], end = beg + rowlen[i];
    float a0 = 0.f, a1 = 0.f;
    int e = beg + lane;
    for (; e + 4 < end; e += 8) {
        int s0 = part2[e];
        int s1 = part2[e + 4];
        float2 v0 = unpack2(xw[s0]);
        float2 v1 = unpack2(xw[s1]);
        a0 += v0.x + v1.x;
        a1 += v0.y + v1.y;
    }
    if (e < end) {
        float2 v = unpack2(xw[part2[e]]);
        a0 += v.x; a1 += v.y;
    }
    if (lane == 0) {
        float2 self = unpack2(xw[i]);
        a0 += self.x; a1 += self.y;
    }
    a0 += __shfl_xor(a0, 1); a0 += __shfl_xor(a0, 2);
    a1 += __shfl_xor(a1, 1); a1 += __shfl_xor(a1, 2);
    float di = dinv[i];
    a0 *= di; a1 *= di;
    float z0 = 0.f, z1 = 0.f, z2 = 0.f;
    int j0 = lane << 4;
#pragma unroll
    for (int jj = 0; jj < 16; ++jj) {
        int j = j0 + jj;
        float h = fmaf(a0, sW1[j], fmaf(a1, sW1[64 + j], sb1[j]));
        h = fmaxf(h, 0.f);
        z0 = fmaf(h, sW2[3 * j],     z0);
        z1 = fmaf(h, sW2[3 * j + 1], z1);
        z2 = fmaf(h, sW2[3 * j + 2], z2);
    }
    z0 += __shfl_xor(z0, 1); z0 += __shfl_xor(z0, 2);
    z1 += __shfl_xor(z1, 1); z1 += __shfl_xor(z1, 2);
    z2 += __shfl_xor(z2, 1); z2 += __shfl_xor(z2, 2);
    if (lane == 0)
        zw[i] = make_uint2(pack2(di * z0, di * z1), pack2(di * z2, 0.f));
}

// layer-2: 4 lanes/node, unrolled 8B gathers + butterfly; epilogue + wave pooling
__global__ void __launch_bounds__(256) k_bout(
        const int* __restrict__ part2, const int* __restrict__ rowstart,
        const int* __restrict__ rowlen,
        const float* __restrict__ dinv, const uint2* __restrict__ zw,
        const float* __restrict__ b2, const int* __restrict__ batch,
        float* __restrict__ pooled, float* __restrict__ cnt, int n) {
    int tid = blockIdx.x * 256 + threadIdx.x;
    int i = tid >> 2, lane = tid & 3;
    float o0 = 0.f, o1 = 0.f, o2 = 0.f, vc = 0.f;
    int g = -1;
    if (i < n) {
        int beg = rowstart[i], end = beg + rowlen[i];
        float a0 = 0.f, a1 = 0.f, a2 = 0.f;
        int e = beg + lane;
        for (; e + 4 < end; e += 8) {
            int s0 = part2[e];
            int s1 = part2[e + 4];
            uint2 u0 = zw[s0];
            uint2 u1 = zw[s1];
            float2 p0 = unpack2(u0.x), p1 = unpack2(u1.x);
            a0 += p0.x + p1.x;
            a1 += p0.y + p1.y;
            a2 += unpack2(u0.y).x + unpack2(u1.y).x;
        }
        if (e < end) {
            uint2 u = zw[part2[e]];
            float2 p = unpack2(u.x);
            a0 += p.x; a1 += p.y; a2 += unpack2(u.y).x;
        }
        if (lane == 0) {
            uint2 u = zw[i];
            float2 p = unpack2(u.x);
            a0 += p.x; a1 += p.y; a2 += unpack2(u.y).x;
        }
        a0 += __shfl_xor(a0, 1); a0 += __shfl_xor(a0, 2);
        a1 += __shfl_xor(a1, 1); a1 += __shfl_xor(a1, 2);
        a2 += __shfl_xor(a2, 1); a2 += __shfl_xor(a2, 2);
        if (lane == 0) {
            float di = dinv[i];
            o0 = fmaf(di, a0, b2[0]);
            o1 = fmaf(di, a1, b2[1]);
            o2 = fmaf(di, a2, b2[2]);
            vc = 1.f;
        }
        g = batch[i];
    }
    int g0 = __shfl(g, 0);
    bool uni = __all(g == g0);
    if (uni) {
        for (int off = 32; off; off >>= 1) {
            o0 += __shfl_down(o0, off);
            o1 += __shfl_down(o1, off);
            o2 += __shfl_down(o2, off);
            vc += __shfl_down(vc, off);
        }
        if ((threadIdx.x & 63) == 0 && g0 >= 0) {
            atomicAdd(&pooled[3 * g0],     o0);
            atomicAdd(&pooled[3 * g0 + 1], o1);
            atomicAdd(&pooled[3 * g0 + 2], o2);
            atomicAdd(&cnt[g0], vc);
        }
    } else if (g >= 0 && lane == 0) {
        atomicAdd(&pooled[3 * g],     o0);
        atomicAdd(&pooled[3 * g + 1], o1);
        atomicAdd(&pooled[3 * g + 2], o2);
        atomicAdd(&cnt[g], 1.f);
    }
}

__global__ void k_out(const float* __restrict__ pooled, const float* __restrict__ cnt,
                      float* __restrict__ out, int G) {
    int g = blockIdx.x * blockDim.x + threadIdx.x;
    if (g >= G) return;
    float c = fmaxf(cnt[g], 1.0f);
    float p0 = pooled[3 * g] / c, p1 = pooled[3 * g + 1] / c, p2 = pooled[3 * g + 2] / c;
    float m = fmaxf(p0, fmaxf(p1, p2));
    float s = expf(p0 - m) + expf(p1 - m) + expf(p2 - m);
    float l = logf(s);
    out[3 * g]     = p0 - m - l;
    out[3 * g + 1] = p1 - m - l;
    out[3 * g + 2] = p2 - m - l;
}

// ============ PATH B: fallback (atomic scatter, f32) ============

__global__ void kB_deg(const int* __restrict__ dst, float* __restrict__ deg, int E) {
    int i = blockIdx.x * blockDim.x + threadIdx.x;
    if (i < E) atomicAdd(&deg[dst[i]], 1.0f);
}

__global__ void kB_dinv(float* __restrict__ deg, int n) {
    int i = blockIdx.x * blockDim.x + threadIdx.x;
    if (i < n) deg[i] = rsqrtf(deg[i] + 1.0f);
}

__global__ void kB_agg1(const int* __restrict__ src, const int* __restrict__ dst,
                        const float* __restrict__ dinv, const float* __restrict__ x,
                        float* __restrict__ agg1, int E) {
    int i = blockIdx.x * blockDim.x + threadIdx.x;
    if (i >= E) return;
    int s = src[i], d = dst[i];
    float w = dinv[s] * dinv[d];
    float2 xs = *reinterpret_cast<const float2*>(&x[2 * s]);
    atomicAdd(&agg1[2 * d],     w * xs.x);
    atomicAdd(&agg1[2 * d + 1], w * xs.y);
}

__global__ void kB_z(const float* __restrict__ agg1, const float* __restrict__ x,
                     const float* __restrict__ dinv,
                     const float* __restrict__ W1, const float* __restrict__ b1,
                     const float* __restrict__ W2, float* __restrict__ z, int n) {
    __shared__ float sW1[128], sb1[64], sW2[192];
    for (int t = threadIdx.x; t < 128; t += blockDim.x) sW1[t] = W1[t];
    for (int t = threadIdx.x; t < 64;  t += blockDim.x) sb1[t] = b1[t];
    for (int t = threadIdx.x; t < 192; t += blockDim.x) sW2[t] = W2[t];
    __syncthreads();
    int i = blockIdx.x * blockDim.x + threadIdx.x;
    if (i >= n) return;
    float di = dinv[i], w = di * di;
    float2 xs = *reinterpret_cast<const float2*>(&x[2 * i]);
    float a0 = agg1[2 * i]     + w * xs.x;
    float a1 = agg1[2 * i + 1] + w * xs.y;
    float z0 = 0.f, z1 = 0.f, z2 = 0.f;
#pragma unroll
    for (int j = 0; j < 64; ++j) {
        float h = fmaf(a0, sW1[j], fmaf(a1, sW1[64 + j], sb1[j]));
        h = fmaxf(h, 0.f);
        z0 = fmaf(h, sW2[3 * j],     z0);
        z1 = fmaf(h, sW2[3 * j + 1], z1);
        z2 = fmaf(h, sW2[3 * j + 2], z2);
    }
    z[3 * i] = z0; z[3 * i + 1] = z1; z[3 * i + 2] = z2;
}

__global__ void kB_agg2(const int* __restrict__ src, const int* __restrict__ dst,
                        const float* __restrict__ dinv, const float* __restrict__ z,
                        float* __restrict__ agg2, int E) {
    int i = blockIdx.x * blockDim.x + threadIdx.x;
    if (i >= E) return;
    int s = src[i], d = dst[i];
    float w = dinv[s] * dinv[d];
    atomicAdd(&agg2[3 * d],     w * z[3 * s]);
    atomicAdd(&agg2[3 * d + 1], w * z[3 * s + 1]);
    atomicAdd(&agg2[3 * d + 2], w * z[3 * s + 2]);
}

__global__ void kB_pool(const float* __restrict__ agg2, const float* __restrict__ z,
                        const float* __restrict__ dinv, const float* __restrict__ b2,
                        const int* __restrict__ batch,
                        float* __restrict__ pooled, float* __restrict__ cnt, int n) {
    int i = blockIdx.x * blockDim.x + threadIdx.x;
    if (i >= n) return;
    float di = dinv[i], w = di * di;
    float o0 = agg2[3 * i]     + w * z[3 * i]     + b2[0];
    float o1 = agg2[3 * i + 1] + w * z[3 * i + 1] + b2[1];
    float o2 = agg2[3 * i + 2] + w * z[3 * i + 2] + b2[2];
    int g = batch[i];
    atomicAdd(&pooled[3 * g],     o0);
    atomicAdd(&pooled[3 * g + 1], o1);
    atomicAdd(&pooled[3 * g + 2], o2);
    atomicAdd(&cnt[g], 1.0f);
}

// ============ launch ============

extern "C" void kernel_launch(void* const* d_in, const int* in_sizes, int n_in,
                              void* d_out, int out_size, void* d_ws, size_t ws_size,
                              hipStream_t stream) {
    const float* x     = (const float*)d_in[0];
    const int*   ei    = (const int*)  d_in[1];
    const int*   batch = (const int*)  d_in[2];
    const float* W1    = (const float*)d_in[3];
    const float* b1    = (const float*)d_in[4];
    const float* W2    = (const float*)d_in[5];
    const float* b2    = (const float*)d_in[6];
    float*       out   = (float*)d_out;

    const int n = in_sizes[2];
    const int E = in_sizes[1] / 2;
    const int G = out_size / 3;
    const int* src = ei;
    const int* dst = ei + E;
    const int B = 256;

    const int nbuk  = (n + BUCK - 1) >> SH;
    const int chunk = (((E + NBLK - 1) / NBLK) + 3) & ~3;   // 4-aligned chunks

    // statistical overflow guard for fixed-cap buckets: mean + 8*sigma + 64 <= CAP
    double mean = (double)E / (double)nbuk;
    bool cap_ok = (mean + 8.0 * sqrt(mean > 1.0 ? mean : 1.0) + 64.0) <= (double)CAP;

    // Path-A workspace layout (4B units)
    size_t o = 0;
    size_t off_bcnt = o; o += 512;            // bucket fill counts (zeroed)
    size_t off_pool = o; o += (size_t)3 * G;  // zeroed
    size_t off_cnt  = o; o += G;              // zeroed
    size_t zeroA = o;
    size_t off_part = o; o += (size_t)nbuk * CAP;
    size_t off_p2   = o; o += (size_t)nbuk * CAP;
    size_t off_row  = o; o += n;
    size_t off_len  = o; o += n;
    size_t off_dinv = o; o += n;
    size_t off_xw   = o; o += n;              // packed half2
    o = (o + 1) & ~(size_t)1;                 // 8B-align zw
    size_t off_zw   = o; o += (size_t)2 * n;  // packed uint2
    size_t needA = o * 4;

    if (ws_size >= needA && nbuk <= NBUK_MAX && cap_ok) {
        int*      bcnt   = (int*)d_ws + off_bcnt;
        int*      part   = (int*)d_ws + off_part;
        int*      part2  = (int*)d_ws + off_p2;
        int*      row    = (int*)d_ws + off_row;
        int*      rlen   = (int*)d_ws + off_len;
        float*    dinv   = (float*)d_ws + off_dinv;
        unsigned* xw     = (unsigned*)((int*)d_ws + off_xw);
        uint2*    zw     = (uint2*)((int*)d_ws + off_zw);
        float*    pooled = (float*)d_ws + off_pool;
        float*    cnt    = (float*)d_ws + off_cnt;

        hipMemsetAsync(d_ws, 0, zeroA * 4, stream);   // bcnt + pooled + cnt
        k_pfill<<<NBLK, PTH, 0, stream>>>(src, dst, bcnt, part, E, nbuk, chunk);
        k_prep <<<nbuk, 512, 0, stream>>>(part, bcnt, x, part2, row, rlen, dinv, xw, n);
        k_bz   <<<(4 * n + 255) / 256, 256, 0, stream>>>(part2, row, rlen, dinv, xw,
                                                         W1, b1, W2, zw, n);
        k_bout <<<(4 * n + 255) / 256, 256, 0, stream>>>(part2, row, rlen, dinv, zw,
                                                         b2, batch, pooled, cnt, n);
        k_out  <<<(G + B - 1) / B, B, 0, stream>>>(pooled, cnt, out, G);
    } else {
        float* ws     = (float*)d_ws;
        float* deg    = ws;
        float* agg1   = deg + n;
        float* agg2   = agg1 + 2 * (size_t)n;
        float* pooled = agg2 + 3 * (size_t)n;
        float* cnt    = pooled + 3 * (size_t)G;
        float* zf     = cnt + G;

        size_t zero_floats = (size_t)6 * n + (size_t)4 * G;
        hipMemsetAsync(ws, 0, zero_floats * sizeof(float), stream);
        kB_deg <<<(E + B - 1) / B, B, 0, stream>>>(dst, deg, E);
        kB_dinv<<<(n + B - 1) / B, B, 0, stream>>>(deg, n);
        kB_agg1<<<(E + B - 1) / B, B, 0, stream>>>(src, dst, deg, x, agg1, E);
        kB_z   <<<(n + B - 1) / B, B, 0, stream>>>(agg1, x, deg, W1, b1, W2, zf, n);
        kB_agg2<<<(E + B - 1) / B, B, 0, stream>>>(src, dst, deg, zf, agg2, E);
        kB_pool<<<(n + B - 1) / B, B, 0, stream>>>(agg2, zf, deg, b2, batch, pooled, cnt, n);
        k_out  <<<(G + B - 1) / B, B, 0, stream>>>(pooled, cnt, out, G);
    }
}

// Round 12
// 123.884 us; speedup vs baseline: 1.4106x; 1.0051x over previous
//
#include <hip/hip_runtime.h>
#include <hip/hip_fp16.h>
#include <math.h>

#define NBLK 1024         // partition blocks
#define PTH  512          // pfill threads
#define SH   9
#define BUCK 512          // nodes per bucket = 1<<SH
#define NBUK_MAX 512
#define CAP  10240        // fixed per-bucket region capacity (multiple of 4)
#define TILE 4096         // pfill per-tile staged edges
#define ECAP 4096         // staged part2 entries per gather block (64 nodes; mean 1024)

__device__ __forceinline__ unsigned pack2(float a, float b) {
    __half ha = __float2half_rn(a), hb = __float2half_rn(b);
    unsigned short ua = *reinterpret_cast<unsigned short*>(&ha);
    unsigned short ub = *reinterpret_cast<unsigned short*>(&hb);
    return ((unsigned)ub << 16) | ua;
}
__device__ __forceinline__ float2 unpack2(unsigned u) {
    unsigned short ua = (unsigned short)(u & 0xffff), ub = (unsigned short)(u >> 16);
    __half ha = *reinterpret_cast<__half*>(&ua), hb = *reinterpret_cast<__half*>(&ub);
    return make_float2(__half2float(ha), __half2float(hb));
}

// ============ PATH A: single-pass bucket sort -> CSR -> LDS-staged-index gathers ============

// tile-local LDS counting sort; per-tile global reservation via bcnt; coalesced copy-out
__global__ void __launch_bounds__(PTH) k_pfill(const int* __restrict__ src,
                                               const int* __restrict__ dst,
                                               int* __restrict__ bcnt,
                                               int* __restrict__ part,
                                               int E, int nbuk, int chunk) {
    __shared__ int hist[NBUK_MAX];
    __shared__ int scn[NBUK_MAX];
    __shared__ int lcur[NBUK_MAX];
    __shared__ int resv[NBUK_MAX];
    __shared__ int lout[TILE];
    __shared__ unsigned short lbk[TILE];
    int t = threadIdx.x, b = blockIdx.x;
    int beg = b * chunk, end = min(beg + chunk, E);
    for (int tb = beg; tb < end; tb += TILE) {      // tb stays 4-aligned
        int te = min(tb + TILE, end), cnt = te - tb;
        int nq = cnt >> 2;
        for (int u = t; u < nbuk; u += PTH) hist[u] = 0;
        __syncthreads();
        for (int q = t; q < nq; q += PTH) {
            int4 d4 = *reinterpret_cast<const int4*>(&dst[tb + (q << 2)]);
            atomicAdd(&hist[d4.x >> SH], 1);
            atomicAdd(&hist[d4.y >> SH], 1);
            atomicAdd(&hist[d4.z >> SH], 1);
            atomicAdd(&hist[d4.w >> SH], 1);
        }
        for (int i = tb + (nq << 2) + t; i < te; i += PTH)
            atomicAdd(&hist[dst[i] >> SH], 1);
        __syncthreads();
        int v = (t < nbuk) ? hist[t] : 0;
        scn[t] = v; __syncthreads();
        for (int off = 1; off < PTH; off <<= 1) {
            int u = (t >= off) ? scn[t - off] : 0;
            __syncthreads();
            scn[t] += u;
            __syncthreads();
        }
        if (t < nbuk) {
            lcur[t] = scn[t] - hist[t];
            resv[t] = (hist[t] > 0) ? atomicAdd(&bcnt[t], hist[t]) : 0;
        }
        __syncthreads();
        for (int q = t; q < nq; q += PTH) {
            int base = tb + (q << 2);
            int4 d4 = *reinterpret_cast<const int4*>(&dst[base]);
            int4 s4 = *reinterpret_cast<const int4*>(&src[base]);
            int bk, p;
            bk = d4.x >> SH; p = atomicAdd(&lcur[bk], 1);
            lout[p] = (s4.x << SH) | (d4.x & (BUCK - 1)); lbk[p] = (unsigned short)bk;
            bk = d4.y >> SH; p = atomicAdd(&lcur[bk], 1);
            lout[p] = (s4.y << SH) | (d4.y & (BUCK - 1)); lbk[p] = (unsigned short)bk;
            bk = d4.z >> SH; p = atomicAdd(&lcur[bk], 1);
            lout[p] = (s4.z << SH) | (d4.z & (BUCK - 1)); lbk[p] = (unsigned short)bk;
            bk = d4.w >> SH; p = atomicAdd(&lcur[bk], 1);
            lout[p] = (s4.w << SH) | (d4.w & (BUCK - 1)); lbk[p] = (unsigned short)bk;
        }
        for (int i = tb + (nq << 2) + t; i < te; i += PTH) {
            int d = dst[i];
            int bk = d >> SH;
            int p = atomicAdd(&lcur[bk], 1);
            lout[p] = (src[i] << SH) | (d & (BUCK - 1)); lbk[p] = (unsigned short)bk;
        }
        __syncthreads();
        for (int j = t; j < cnt; j += PTH) {
            int bk = lbk[j];
            part[bk * CAP + resv[bk] + (j - (scn[bk] - hist[bk]))] = lout[j];
        }
        __syncthreads();
    }
}

// per bucket: hist -> scan -> LDS-staged scatter into dst-sorted part2;
// rowstart (absolute), rowlen, dinv, xw = half2(dinv*x)
__global__ void __launch_bounds__(512) k_prep(
        const int* __restrict__ part, const int* __restrict__ bcnt,
        const float* __restrict__ x,
        int* __restrict__ part2, int* __restrict__ rowstart, int* __restrict__ rowlen,
        float* __restrict__ dinv, unsigned* __restrict__ xw, int n) {
    __shared__ int hist[BUCK];
    __shared__ int s[BUCK];
    __shared__ int cur[BUCK];
    __shared__ int outbuf[CAP];
    int t = threadIdx.x, b = blockIdx.x;
    hist[t] = 0;
    __syncthreads();
    int beg = b * CAP;                 // 4-aligned
    int cnt = bcnt[b];
    int end = beg + cnt;
    int nq = cnt >> 2;
    for (int q = t; q < nq; q += 512) {
        int4 e4 = *reinterpret_cast<const int4*>(&part[beg + (q << 2)]);
        atomicAdd(&hist[e4.x & (BUCK - 1)], 1);
        atomicAdd(&hist[e4.y & (BUCK - 1)], 1);
        atomicAdd(&hist[e4.z & (BUCK - 1)], 1);
        atomicAdd(&hist[e4.w & (BUCK - 1)], 1);
    }
    for (int i = beg + (nq << 2) + t; i < end; i += 512)
        atomicAdd(&hist[part[i] & (BUCK - 1)], 1);
    __syncthreads();
    s[t] = hist[t];
    __syncthreads();
    for (int d = 1; d < 512; d <<= 1) {
        int v = (t >= d) ? s[t - d] : 0;
        __syncthreads();
        s[t] += v;
        __syncthreads();
    }
    int excl = s[t] - hist[t];
    cur[t] = excl;
    int node = (b << SH) + t;
    if (node < n) {
        rowstart[node] = beg + excl;
        rowlen[node]   = hist[t];
        float di = rsqrtf((float)hist[t] + 1.0f);
        dinv[node] = di;
        float2 xs = *reinterpret_cast<const float2*>(&x[2 * node]);
        xw[node] = pack2(di * xs.x, di * xs.y);
    }
    __syncthreads();
    for (int q = t; q < nq; q += 512) {
        int4 e4 = *reinterpret_cast<const int4*>(&part[beg + (q << 2)]);
        int p;
        p = atomicAdd(&cur[e4.x & (BUCK - 1)], 1); outbuf[p] = e4.x >> SH;
        p = atomicAdd(&cur[e4.y & (BUCK - 1)], 1); outbuf[p] = e4.y >> SH;
        p = atomicAdd(&cur[e4.z & (BUCK - 1)], 1); outbuf[p] = e4.z >> SH;
        p = atomicAdd(&cur[e4.w & (BUCK - 1)], 1); outbuf[p] = e4.w >> SH;
    }
    for (int i = beg + (nq << 2) + t; i < end; i += 512) {
        int e = part[i];
        int p = atomicAdd(&cur[e & (BUCK - 1)], 1);
        outbuf[p] = e >> SH;
    }
    __syncthreads();
    for (int i = t; i < cnt; i += 512)
        part2[beg + i] = outbuf[i];                 // coalesced
}

// layer-1: block = 64 nodes (contiguous part2 range staged in LDS) × 4 lanes/node;
// gathers read indices from LDS; MLP 16 hidden/lane
__global__ void __launch_bounds__(256) k_bz(
        const int* __restrict__ part2, const int* __restrict__ rowstart,
        const int* __restrict__ rowlen,
        const float* __restrict__ dinv, const unsigned* __restrict__ xw,
        const float* __restrict__ W1, const float* __restrict__ b1,
        const float* __restrict__ W2, uint2* __restrict__ zw, int n) {
    __shared__ float sW1[128], sb1[64], sW2[192];
    __shared__ int sidx[ECAP];
    __shared__ int sinfo[2];           // ebeg, elen (or -1 if overflow)
    for (int t = threadIdx.x; t < 128; t += 256) sW1[t] = W1[t];
    for (int t = threadIdx.x; t < 64;  t += 256) sb1[t] = b1[t];
    for (int t = threadIdx.x; t < 192; t += 256) sW2[t] = W2[t];
    int nbase = blockIdx.x * 64;
    if (threadIdx.x == 0) {
        int last = min(nbase + 63, n - 1);
        int eb = rowstart[nbase];
        int el = rowstart[last] + rowlen[last] - eb;
        sinfo[0] = eb;
        sinfo[1] = (el <= ECAP) ? el : -1;
    }
    __syncthreads();
    int ebeg = sinfo[0], elen = sinfo[1];
    bool use_lds = (elen >= 0);
    if (use_lds) {
        for (int j = threadIdx.x; j < elen; j += 256)
            sidx[j] = part2[ebeg + j];              // fully coalesced
    }
    __syncthreads();
    int i = nbase + (threadIdx.x >> 2), lane = threadIdx.x & 3;
    if (i >= n) return;
    int beg = rowstart[i], end = beg + rowlen[i];
    float a0 = 0.f, a1 = 0.f;
    int e = beg + lane;
    if (use_lds) {
        for (; e + 4 < end; e += 8) {
            int s0 = sidx[e - ebeg];
            int s1 = sidx[e + 4 - ebeg];
            float2 v0 = unpack2(xw[s0]);
            float2 v1 = unpack2(xw[s1]);
            a0 += v0.x + v1.x;
            a1 += v0.y + v1.y;
        }
        if (e < end) {
            float2 v = unpack2(xw[sidx[e - ebeg]]);
            a0 += v.x; a1 += v.y;
        }
    } else {
        for (; e + 4 < end; e += 8) {
            int s0 = part2[e];
            int s1 = part2[e + 4];
            float2 v0 = unpack2(xw[s0]);
            float2 v1 = unpack2(xw[s1]);
            a0 += v0.x + v1.x;
            a1 += v0.y + v1.y;
        }
        if (e < end) {
            float2 v = unpack2(xw[part2[e]]);
            a0 += v.x; a1 += v.y;
        }
    }
    if (lane == 0) {
        float2 self = unpack2(xw[i]);
        a0 += self.x; a1 += self.y;
    }
    a0 += __shfl_xor(a0, 1); a0 += __shfl_xor(a0, 2);
    a1 += __shfl_xor(a1, 1); a1 += __shfl_xor(a1, 2);
    float di = dinv[i];
    a0 *= di; a1 *= di;
    float z0 = 0.f, z1 = 0.f, z2 = 0.f;
    int j0 = lane << 4;
#pragma unroll
    for (int jj = 0; jj < 16; ++jj) {
        int j = j0 + jj;
        float h = fmaf(a0, sW1[j], fmaf(a1, sW1[64 + j], sb1[j]));
        h = fmaxf(h, 0.f);
        z0 = fmaf(h, sW2[3 * j],     z0);
        z1 = fmaf(h, sW2[3 * j + 1], z1);
        z2 = fmaf(h, sW2[3 * j + 2], z2);
    }
    z0 += __shfl_xor(z0, 1); z0 += __shfl_xor(z0, 2);
    z1 += __shfl_xor(z1, 1); z1 += __shfl_xor(z1, 2);
    z2 += __shfl_xor(z2, 1); z2 += __shfl_xor(z2, 2);
    if (lane == 0)
        zw[i] = make_uint2(pack2(di * z0, di * z1), pack2(di * z2, 0.f));
}

// layer-2: same LDS-staged-index structure; epilogue + sorted-batch wave pooling
__global__ void __launch_bounds__(256) k_bout(
        const int* __restrict__ part2, const int* __restrict__ rowstart,
        const int* __restrict__ rowlen,
        const float* __restrict__ dinv, const uint2* __restrict__ zw,
        const float* __restrict__ b2, const int* __restrict__ batch,
        float* __restrict__ pooled, float* __restrict__ cnt, int n) {
    __shared__ int sidx[ECAP];
    __shared__ int sinfo[2];
    int nbase = blockIdx.x * 64;
    if (threadIdx.x == 0) {
        int last = min(nbase + 63, n - 1);
        int eb = rowstart[nbase];
        int el = rowstart[last] + rowlen[last] - eb;
        sinfo[0] = eb;
        sinfo[1] = (el <= ECAP) ? el : -1;
    }
    __syncthreads();
    int ebeg = sinfo[0], elen = sinfo[1];
    bool use_lds = (elen >= 0);
    if (use_lds) {
        for (int j = threadIdx.x; j < elen; j += 256)
            sidx[j] = part2[ebeg + j];
    }
    __syncthreads();
    int i = nbase + (threadIdx.x >> 2), lane = threadIdx.x & 3;
    float o0 = 0.f, o1 = 0.f, o2 = 0.f, vc = 0.f;
    int g = -1;
    if (i < n) {
        int beg = rowstart[i], end = beg + rowlen[i];
        float a0 = 0.f, a1 = 0.f, a2 = 0.f;
        int e = beg + lane;
        if (use_lds) {
            for (; e + 4 < end; e += 8) {
                int s0 = sidx[e - ebeg];
                int s1 = sidx[e + 4 - ebeg];
                uint2 u0 = zw[s0];
                uint2 u1 = zw[s1];
                float2 p0 = unpack2(u0.x), p1 = unpack2(u1.x);
                a0 += p0.x + p1.x;
                a1 += p0.y + p1.y;
                a2 += unpack2(u0.y).x + unpack2(u1.y).x;
            }
            if (e < end) {
                uint2 u = zw[sidx[e - ebeg]];
                float2 p = unpack2(u.x);
                a0 += p.x; a1 += p.y; a2 += unpack2(u.y).x;
            }
        } else {
            for (; e + 4 < end; e += 8) {
                int s0 = part2[e];
                int s1 = part2[e + 4];
                uint2 u0 = zw[s0];
                uint2 u1 = zw[s1];
                float2 p0 = unpack2(u0.x), p1 = unpack2(u1.x);
                a0 += p0.x + p1.x;
                a1 += p0.y + p1.y;
                a2 += unpack2(u0.y).x + unpack2(u1.y).x;
            }
            if (e < end) {
                uint2 u = zw[part2[e]];
                float2 p = unpack2(u.x);
                a0 += p.x; a1 += p.y; a2 += unpack2(u.y).x;
            }
        }
        if (lane == 0) {
            uint2 u = zw[i];
            float2 p = unpack2(u.x);
            a0 += p.x; a1 += p.y; a2 += unpack2(u.y).x;
        }
        a0 += __shfl_xor(a0, 1); a0 += __shfl_xor(a0, 2);
        a1 += __shfl_xor(a1, 1); a1 += __shfl_xor(a1, 2);
        a2 += __shfl_xor(a2, 1); a2 += __shfl_xor(a2, 2);
        if (lane == 0) {
            float di = dinv[i];
            o0 = fmaf(di, a0, b2[0]);
            o1 = fmaf(di, a1, b2[1]);
            o2 = fmaf(di, a2, b2[2]);
            vc = 1.f;
        }
        g = batch[i];
    }
    int g0 = __shfl(g, 0);
    bool uni = __all(g == g0);
    if (uni) {
        for (int off = 32; off; off >>= 1) {
            o0 += __shfl_down(o0, off);
            o1 += __shfl_down(o1, off);
            o2 += __shfl_down(o2, off);
            vc += __shfl_down(vc, off);
        }
        if ((threadIdx.x & 63) == 0 && g0 >= 0) {
            atomicAdd(&pooled[3 * g0],     o0);
            atomicAdd(&pooled[3 * g0 + 1], o1);
            atomicAdd(&pooled[3 * g0 + 2], o2);
            atomicAdd(&cnt[g0], vc);
        }
    } else if (g >= 0 && lane == 0) {
        atomicAdd(&pooled[3 * g],     o0);
        atomicAdd(&pooled[3 * g + 1], o1);
        atomicAdd(&pooled[3 * g + 2], o2);
        atomicAdd(&cnt[g], 1.f);
    }
}

__global__ void k_out(const float* __restrict__ pooled, const float* __restrict__ cnt,
                      float* __restrict__ out, int G) {
    int g = blockIdx.x * blockDim.x + threadIdx.x;
    if (g >= G) return;
    float c = fmaxf(cnt[g], 1.0f);
    float p0 = pooled[3 * g] / c, p1 = pooled[3 * g + 1] / c, p2 = pooled[3 * g + 2] / c;
    float m = fmaxf(p0, fmaxf(p1, p2));
    float s = expf(p0 - m) + expf(p1 - m) + expf(p2 - m);
    float l = logf(s);
    out[3 * g]     = p0 - m - l;
    out[3 * g + 1] = p1 - m - l;
    out[3 * g + 2] = p2 - m - l;
}

// ============ PATH B: fallback (atomic scatter, f32) ============

__global__ void kB_deg(const int* __restrict__ dst, float* __restrict__ deg, int E) {
    int i = blockIdx.x * blockDim.x + threadIdx.x;
    if (i < E) atomicAdd(&deg[dst[i]], 1.0f);
}

__global__ void kB_dinv(float* __restrict__ deg, int n) {
    int i = blockIdx.x * blockDim.x + threadIdx.x;
    if (i < n) deg[i] = rsqrtf(deg[i] + 1.0f);
}

__global__ void kB_agg1(const int* __restrict__ src, const int* __restrict__ dst,
                        const float* __restrict__ dinv, const float* __restrict__ x,
                        float* __restrict__ agg1, int E) {
    int i = blockIdx.x * blockDim.x + threadIdx.x;
    if (i >= E) return;
    int s = src[i], d = dst[i];
    float w = dinv[s] * dinv[d];
    float2 xs = *reinterpret_cast<const float2*>(&x[2 * s]);
    atomicAdd(&agg1[2 * d],     w * xs.x);
    atomicAdd(&agg1[2 * d + 1], w * xs.y);
}

__global__ void kB_z(const float* __restrict__ agg1, const float* __restrict__ x,
                     const float* __restrict__ dinv,
                     const float* __restrict__ W1, const float* __restrict__ b1,
                     const float* __restrict__ W2, float* __restrict__ z, int n) {
    __shared__ float sW1[128], sb1[64], sW2[192];
    for (int t = threadIdx.x; t < 128; t += blockDim.x) sW1[t] = W1[t];
    for (int t = threadIdx.x; t < 64;  t += blockDim.x) sb1[t] = b1[t];
    for (int t = threadIdx.x; t < 192; t += blockDim.x) sW2[t] = W2[t];
    __syncthreads();
    int i = blockIdx.x * blockDim.x + threadIdx.x;
    if (i >= n) return;
    float di = dinv[i], w = di * di;
    float2 xs = *reinterpret_cast<const float2*>(&x[2 * i]);
    float a0 = agg1[2 * i]     + w * xs.x;
    float a1 = agg1[2 * i + 1] + w * xs.y;
    float z0 = 0.f, z1 = 0.f, z2 = 0.f;
#pragma unroll
    for (int j = 0; j < 64; ++j) {
        float h = fmaf(a0, sW1[j], fmaf(a1, sW1[64 + j], sb1[j]));
        h = fmaxf(h, 0.f);
        z0 = fmaf(h, sW2[3 * j],     z0);
        z1 = fmaf(h, sW2[3 * j + 1], z1);
        z2 = fmaf(h, sW2[3 * j + 2], z2);
    }
    z[3 * i] = z0; z[3 * i + 1] = z1; z[3 * i + 2] = z2;
}

__global__ void kB_agg2(const int* __restrict__ src, const int* __restrict__ dst,
                        const float* __restrict__ dinv, const float* __restrict__ z,
                        float* __restrict__ agg2, int E) {
    int i = blockIdx.x * blockDim.x + threadIdx.x;
    if (i >= E) return;
    int s = src[i], d = dst[i];
    float w = dinv[s] * dinv[d];
    atomicAdd(&agg2[3 * d],     w * z[3 * s]);
    atomicAdd(&agg2[3 * d + 1], w * z[3 * s + 1]);
    atomicAdd(&agg2[3 * d + 2], w * z[3 * s + 2]);
}

__global__ void kB_pool(const float* __restrict__ agg2, const float* __restrict__ z,
                        const float* __restrict__ dinv, const float* __restrict__ b2,
                        const int* __restrict__ batch,
                        float* __restrict__ pooled, float* __restrict__ cnt, int n) {
    int i = blockIdx.x * blockDim.x + threadIdx.x;
    if (i >= n) return;
    float di = dinv[i], w = di * di;
    float o0 = agg2[3 * i]     + w * z[3 * i]     + b2[0];
    float o1 = agg2[3 * i + 1] + w * z[3 * i + 1] + b2[1];
    float o2 = agg2[3 * i + 2] + w * z[3 * i + 2] + b2[2];
    int g = batch[i];
    atomicAdd(&pooled[3 * g],     o0);
    atomicAdd(&pooled[3 * g + 1], o1);
    atomicAdd(&pooled[3 * g + 2], o2);
    atomicAdd(&cnt[g], 1.0f);
}

// ============ launch ============

extern "C" void kernel_launch(void* const* d_in, const int* in_sizes, int n_in,
                              void* d_out, int out_size, void* d_ws, size_t ws_size,
                              hipStream_t stream) {
    const float* x     = (const float*)d_in[0];
    const int*   ei    = (const int*)  d_in[1];
    const int*   batch = (const int*)  d_in[2];
    const float* W1    = (const float*)d_in[3];
    const float* b1    = (const float*)d_in[4];
    const float* W2    = (const float*)d_in[5];
    const float* b2    = (const float*)d_in[6];
    float*       out   = (float*)d_out;

    const int n = in_sizes[2];
    const int E = in_sizes[1] / 2;
    const int G = out_size / 3;
    const int* src = ei;
    const int* dst = ei + E;
    const int B = 256;

    const int nbuk  = (n + BUCK - 1) >> SH;
    const int chunk = (((E + NBLK - 1) / NBLK) + 3) & ~3;   // 4-aligned chunks

    // statistical overflow guard for fixed-cap buckets: mean + 8*sigma + 64 <= CAP
    double mean = (double)E / (double)nbuk;
    bool cap_ok = (mean + 8.0 * sqrt(mean > 1.0 ? mean : 1.0) + 64.0) <= (double)CAP;

    // Path-A workspace layout (4B units)
    size_t o = 0;
    size_t off_bcnt = o; o += 512;            // zeroed
    size_t off_pool = o; o += (size_t)3 * G;  // zeroed
    size_t off_cnt  = o; o += G;              // zeroed
    size_t zeroA = o;
    size_t off_part = o; o += (size_t)nbuk * CAP;
    size_t off_p2   = o; o += (size_t)nbuk * CAP;
    size_t off_row  = o; o += n;
    size_t off_len  = o; o += n;
    size_t off_dinv = o; o += n;
    size_t off_xw   = o; o += n;              // packed half2
    o = (o + 1) & ~(size_t)1;                 // 8B-align zw
    size_t off_zw   = o; o += (size_t)2 * n;  // packed uint2
    size_t needA = o * 4;

    if (ws_size >= needA && nbuk <= NBUK_MAX && cap_ok) {
        int*      bcnt   = (int*)d_ws + off_bcnt;
        int*      part   = (int*)d_ws + off_part;
        int*      part2  = (int*)d_ws + off_p2;
        int*      row    = (int*)d_ws + off_row;
        int*      rlen   = (int*)d_ws + off_len;
        float*    dinv   = (float*)d_ws + off_dinv;
        unsigned* xw     = (unsigned*)((int*)d_ws + off_xw);
        uint2*    zw     = (uint2*)((int*)d_ws + off_zw);
        float*    pooled = (float*)d_ws + off_pool;
        float*    cnt    = (float*)d_ws + off_cnt;

        const int NGB = (n + 63) / 64;        // gather blocks (64 nodes each)

        hipMemsetAsync(d_ws, 0, zeroA * 4, stream);   // bcnt + pooled + cnt
        k_pfill<<<NBLK, PTH, 0, stream>>>(src, dst, bcnt, part, E, nbuk, chunk);
        k_prep <<<nbuk, 512, 0, stream>>>(part, bcnt, x, part2, row, rlen, dinv, xw, n);
        k_bz   <<<NGB, 256, 0, stream>>>(part2, row, rlen, dinv, xw, W1, b1, W2, zw, n);
        k_bout <<<NGB, 256, 0, stream>>>(part2, row, rlen, dinv, zw, b2, batch, pooled, cnt, n);
        k_out  <<<(G + B - 1) / B, B, 0, stream>>>(pooled, cnt, out, G);
    } else {
        float* ws     = (float*)d_ws;
        float* deg    = ws;
        float* agg1   = deg + n;
        float* agg2   = agg1 + 2 * (size_t)n;
        float* pooled = agg2 + 3 * (size_t)n;
        float* cnt    = pooled + 3 * (size_t)G;
        float* zf     = cnt + G;

        size_t zero_floats = (size_t)6 * n + (size_t)4 * G;
        hipMemsetAsync(ws, 0, zero_floats * sizeof(float), stream);
        kB_deg <<<(E + B - 1) / B, B, 0, stream>>>(dst, deg, E);
        kB_dinv<<<(n + B - 1) / B, B, 0, stream>>>(deg, n);
        kB_agg1<<<(E + B - 1) / B, B, 0, stream>>>(src, dst, deg, x, agg1, E);
        kB_z   <<<(n + B - 1) / B, B, 0, stream>>>(agg1, x, deg, W1, b1, W2, zf, n);
        kB_agg2<<<(E + B - 1) / B, B, 0, stream>>>(src, dst, deg, zf, agg2, E);
        kB_pool<<<(n + B - 1) / B, B, 0, stream>>>(agg2, zf, deg, b2, batch, pooled, cnt, n);
        k_out  <<<(G + B - 1) / B, B, 0, stream>>>(pooled, cnt, out, G);
    }
}